// Round 5
// baseline (522.776 us; speedup 1.0000x reference)
//
#include <hip/hip_runtime.h>
#include <hip/hip_bf16.h>
#include <float.h>

#define HEADS 4
#define HID 64
#define HC 256   // HEADS*HID
#define NEG_SLOPE 0.2f
#define EPS 1e-16f

typedef short bf16x8 __attribute__((ext_vector_type(8)));
typedef float f32x4 __attribute__((ext_vector_type(4)));

__device__ __forceinline__ float bflo(unsigned u) { return __uint_as_float(u << 16); }
__device__ __forceinline__ float bfhi(unsigned u) { return __uint_as_float(u & 0xffff0000u); }
__device__ __forceinline__ unsigned packbf2(float a, float b) {
  __hip_bfloat16 ha = __float2bfloat16(a), hb = __float2bfloat16(b);
  unsigned short ua = *reinterpret_cast<unsigned short*>(&ha);
  unsigned short ub = *reinterpret_cast<unsigned short*>(&hb);
  return (unsigned)ua | ((unsigned)ub << 16);
}
// monotone float<->uint order-preserving map (for atomicMax on floats)
__device__ __forceinline__ unsigned fenc(float f) {
  unsigned u = __float_as_uint(f);
  return (u & 0x80000000u) ? ~u : (u | 0x80000000u);
}
__device__ __forceinline__ float fdec(unsigned k) {
  unsigned u = (k & 0x80000000u) ? (k ^ 0x80000000u) : ~k;
  return __uint_as_float(u);
}
// async global->LDS, 16B per lane; LDS dest = wave-uniform base + lane*16
__device__ __forceinline__ void gload_lds16(const void* g, void* l) {
  __builtin_amdgcn_global_load_lds((const __attribute__((address_space(1))) void*)g,
                                   (__attribute__((address_space(3))) void*)l, 16, 0, 0);
}

// ---------------------------------------------------------------------------
// bf16 MFMA GEMM, m97 structure: C[MxN] = A[MxK] @ Bt^T (+bias)(+act).
// Bt is [N][K] bf16. Tile 128x128, BK=32, 4 waves, global_load_lds staging
// (unpadded [128][32] LDS: the 8-way b128 aliasing equals the 128B/cy LDS
// floor, so no padding needed). act: 0=none, 2=sigmoid. K % 32 == 0.
// ---------------------------------------------------------------------------
__global__ void __launch_bounds__(256) mfma_gemm(
    const __hip_bfloat16* __restrict__ A, const __hip_bfloat16* __restrict__ Bt,
    const float* __restrict__ bias, float* __restrict__ Cf,
    __hip_bfloat16* __restrict__ Cb, int M, int N, int K, int act) {
  __shared__ unsigned short As[128 * 32];
  __shared__ unsigned short Bs[128 * 32];
  int tid = threadIdx.x;
  int lane = tid & 63, w = tid >> 6;
  int wm = w & 1, wn = w >> 1;
  int col16 = lane & 15, quad = lane >> 4;
  int row0 = blockIdx.y * 128, col0 = blockIdx.x * 128;
  const unsigned short* Ag = (const unsigned short*)A;
  const unsigned short* Bg = (const unsigned short*)Bt;

  // staging: wave w covers tile rows [32w, 32w+32), 2 insts x 16 rows each;
  // lane l -> row (base + l/4), 16B granule (l&3)
  int sr = (w << 5) + (lane >> 2);
  int sg = (lane & 3) << 3;  // elem offset of 16B granule
  int ar0 = row0 + sr;       if (ar0 >= M) ar0 = M - 1;
  int ar1 = row0 + sr + 16;  if (ar1 >= M) ar1 = M - 1;
  int bc0 = col0 + sr;       if (bc0 >= N) bc0 = N - 1;
  int bc1 = col0 + sr + 16;  if (bc1 >= N) bc1 = N - 1;
  unsigned short* abase0 = &As[(w << 5) * 32];
  unsigned short* abase1 = &As[((w << 5) + 16) * 32];
  unsigned short* bbase0 = &Bs[(w << 5) * 32];
  unsigned short* bbase1 = &Bs[((w << 5) + 16) * 32];

  f32x4 acc[4][4] = {};

  for (int k0 = 0; k0 < K; k0 += 32) {
    gload_lds16(Ag + (size_t)ar0 * K + k0 + sg, abase0);
    gload_lds16(Ag + (size_t)ar1 * K + k0 + sg, abase1);
    gload_lds16(Bg + (size_t)bc0 * K + k0 + sg, bbase0);
    gload_lds16(Bg + (size_t)bc1 * K + k0 + sg, bbase1);
    __syncthreads();
    bf16x8 a[4], b[4];
#pragma unroll
    for (int i = 0; i < 4; i++)
      a[i] = *(const bf16x8*)(&As[(wm * 64 + i * 16 + col16) * 32 + quad * 8]);
#pragma unroll
    for (int j = 0; j < 4; j++)
      b[j] = *(const bf16x8*)(&Bs[(wn * 64 + j * 16 + col16) * 32 + quad * 8]);
#pragma unroll
    for (int i = 0; i < 4; i++)
#pragma unroll
      for (int j = 0; j < 4; j++)
        acc[i][j] = __builtin_amdgcn_mfma_f32_16x16x32_bf16(a[i], b[j], acc[i][j], 0, 0, 0);
    __syncthreads();
  }

#pragma unroll
  for (int i = 0; i < 4; i++) {
#pragma unroll
    for (int j = 0; j < 4; j++) {
      int gc = col0 + wn * 64 + j * 16 + col16;
      if (gc >= N) continue;
      int grb = row0 + wm * 64 + i * 16 + quad * 4;
      float bv = bias ? bias[gc] : 0.f;
#pragma unroll
      for (int r = 0; r < 4; r++) {
        int gr = grb + r;
        if (gr >= M) continue;
        float v = acc[i][j][r] + bv;
        if (act == 2) v = 1.f / (1.f + __expf(-v));
        if (Cb) Cb[(size_t)gr * N + gc] = __float2bfloat16(v);
        else Cf[(size_t)gr * N + gc] = v;
      }
    }
  }
}

// ---------------------------------------------------------------------------
// casts / weight prep
// ---------------------------------------------------------------------------
__global__ void cast_bf16(const float* __restrict__ src, __hip_bfloat16* __restrict__ dst, int count4) {
  int i = blockIdx.x * 256 + threadIdx.x;
  if (i >= count4) return;
  float4 v = *(const float4*)(src + 4 * (size_t)i);
  uint2 pk;
  pk.x = packbf2(v.x, v.y);
  pk.y = packbf2(v.z, v.w);
  *(uint2*)((unsigned*)dst + 2 * (size_t)i) = pk;
}

__global__ void prep_weights(const float* __restrict__ W1, const float* __restrict__ W2,
                             const float* __restrict__ Wm1, const float* __restrict__ Wm2,
                             __hip_bfloat16* __restrict__ W1t, __hip_bfloat16* __restrict__ W2t,
                             __hip_bfloat16* __restrict__ Wm1t, __hip_bfloat16* __restrict__ Wm2t) {
  int i = blockIdx.x * 256 + threadIdx.x;
  if (i < 128 * 256) {  // W1: K=128, N=256
    int nn = i / 128, kk = i - nn * 128;
    W1t[i] = __float2bfloat16(W1[(size_t)kk * 256 + nn]);
    return;
  }
  i -= 128 * 256;
  if (i < 256 * 256) {  // W2
    int nn = i / 256, kk = i - nn * 256;
    W2t[i] = __float2bfloat16(W2[(size_t)kk * 256 + nn]);
    return;
  }
  i -= 256 * 256;
  if (i < 256 * 64) {   // Wm1: K=256, N=64
    int nn = i / 256, kk = i - nn * 256;
    Wm1t[i] = __float2bfloat16(Wm1[(size_t)kk * 64 + nn]);
    return;
  }
  i -= 256 * 64;
  if (i < 64 * 121) {   // Wm2: K=64, N=121
    int nn = i / 64, kk = i - nn * 64;
    Wm2t[i] = __float2bfloat16(Wm2[(size_t)kk * 121 + nn]);
  }
}

// ---------------------------------------------------------------------------
// Attention coefficients + per-head global max of a_s (for softmax bound).
// ---------------------------------------------------------------------------
__global__ void attn_coef(const __hip_bfloat16* __restrict__ h,
                          const float* __restrict__ att_s,
                          const float* __restrict__ att_d,
                          float* __restrict__ a_s, float* __restrict__ a_d,
                          unsigned* __restrict__ gmaxu, int goff, int n) {
  int idx = blockIdx.x * 256 + threadIdx.x;
  int lane = threadIdx.x & 63;
  int node = idx >> 2, hd = idx & 3;
  bool ok = idx < n * HEADS;
  float ss = -FLT_MAX;
  if (ok) {
    const uint4* hp = (const uint4*)((const unsigned short*)h + (size_t)node * HC + hd * HID);
    const float* wsv = att_s + hd * HID;
    const float* wdv = att_d + hd * HID;
    float s0 = 0.f, sd = 0.f;
#pragma unroll
    for (int i = 0; i < 8; i++) {
      uint4 u = hp[i];
      float f[8] = {bflo(u.x), bfhi(u.x), bflo(u.y), bfhi(u.y),
                    bflo(u.z), bfhi(u.z), bflo(u.w), bfhi(u.w)};
#pragma unroll
      for (int j = 0; j < 8; j++) {
        int c = i * 8 + j;
        s0 += f[j] * wsv[c];
        sd += f[j] * wdv[c];
      }
    }
    a_s[idx] = s0;
    a_d[idx] = sd;
    ss = s0;
  }
  // wave-reduce per-head max (lanes l and l^4.. share head = lane&3)
  unsigned key = fenc(ss);
#pragma unroll
  for (int off = 4; off < 64; off <<= 1) {
    unsigned k2 = (unsigned)__shfl_xor((int)key, off);
    if (k2 > key) key = k2;
  }
  if (lane < 4) atomicMax(&gmaxu[goff + hd], key);
}

// ---------------------------------------------------------------------------
// CSR build
// ---------------------------------------------------------------------------
__global__ void deg_init(int* __restrict__ deg, unsigned* __restrict__ gmaxu, int n) {
  int i = blockIdx.x * 256 + threadIdx.x;
  if (i < n) deg[i] = 1;
  if (i < 8) gmaxu[i] = 0u;
}

__global__ void deg_count(const int* __restrict__ ei, int E, int* __restrict__ deg) {
  int i = blockIdx.x * 256 + threadIdx.x;
  if (i < E) atomicAdd(&deg[ei[E + i]], 1);
}

__global__ void __launch_bounds__(256) scan_block(const int* __restrict__ deg,
                                                  int* __restrict__ row_start,
                                                  int* __restrict__ bsum, int n) {
  __shared__ int wt[4];
  int tid = threadIdx.x, lane = tid & 63, w = tid >> 6;
  int i = blockIdx.x * 256 + tid;
  int v = (i < n) ? deg[i] : 0;
  int s = v;
#pragma unroll
  for (int off = 1; off < 64; off <<= 1) {
    int t = __shfl_up(s, off);
    if (lane >= off) s += t;
  }
  if (lane == 63) wt[w] = s;
  __syncthreads();
  int add = 0;
  if (w > 0) add += wt[0];
  if (w > 1) add += wt[1];
  if (w > 2) add += wt[2];
  if (i < n) row_start[i + 1] = s + add;
  if (tid == 0) bsum[blockIdx.x] = wt[0] + wt[1] + wt[2] + wt[3];
}

__global__ void __launch_bounds__(256) scan_partials(int* __restrict__ bsum, int nb) {
  __shared__ int wt[4];
  int tid = threadIdx.x, lane = tid & 63, w = tid >> 6;
  int v = (tid < nb) ? bsum[tid] : 0;
  int s = v;
#pragma unroll
  for (int off = 1; off < 64; off <<= 1) {
    int t = __shfl_up(s, off);
    if (lane >= off) s += t;
  }
  if (lane == 63) wt[w] = s;
  __syncthreads();
  int add = 0;
  if (w > 0) add += wt[0];
  if (w > 1) add += wt[1];
  if (w > 2) add += wt[2];
  if (tid < nb) bsum[tid] = s + add - v;
}

__global__ void finalize_row(int* __restrict__ row_start, const int* __restrict__ bsum_ex,
                             const int* __restrict__ deg, int* __restrict__ cur, int n) {
  int i = blockIdx.x * 256 + threadIdx.x;
  if (i == 0) row_start[0] = 0;
  if (i < n) {
    int v = row_start[i + 1] + bsum_ex[blockIdx.x];
    row_start[i + 1] = v;
    cur[i] = v - deg[i];
  }
}

__global__ void csr_fill(const int* __restrict__ ei, int E, int n,
                         int* __restrict__ cur, int* __restrict__ csr_src) {
  int i = blockIdx.x * 256 + threadIdx.x;
  int Etot = E + n;
  if (i >= Etot) return;
  int s, d;
  if (i < E) { s = ei[i]; d = ei[E + i]; }
  else { s = d = i - E; }
  int pos = atomicAdd(&cur[d], 1);
  csr_src[pos] = s;
}

// ---------------------------------------------------------------------------
// GAT aggregation, single pass: softmax shift m_h = leaky(gmax_src[h]+ad[h])
// is a per-(node,head) upper bound (softmax is shift-invariant, so result is
// mathematically identical to segment-max). Per 64-edge chunk: lane i
// computes its edge's 4 numerators -> LDS; then broadcast accumulation:
// edge src via readlane, weight via LDS broadcast, coalesced 512B row gather
// (lane t owns channels 4t..4t+3). Unrolled x4.
// ---------------------------------------------------------------------------
__global__ void __launch_bounds__(256) gat_aggregate(
    const __hip_bfloat16* __restrict__ hb, const float* __restrict__ a_src,
    const float* __restrict__ a_dst, const int* __restrict__ row_start,
    const int* __restrict__ csr_src, const float* __restrict__ bias,
    const unsigned* __restrict__ gmaxu, int goff,
    __hip_bfloat16* __restrict__ out, int n) {
  __shared__ float plds[4][256];
  int wid = threadIdx.x >> 6;
  int lane = threadIdx.x & 63;
  int qh = lane >> 4;  // head owned by this lane's channels (4*lane..4*lane+3)
  int node = (blockIdx.x << 2) + wid;
  if (node >= n) return;
  float4 adv = *(const float4*)(a_dst + (size_t)node * 4);
  // per-head softmax shift (upper bound on all incoming logits)
  float m0 = fdec(gmaxu[goff + 0]) + adv.x; m0 = fmaxf(m0, NEG_SLOPE * m0);
  float m1 = fdec(gmaxu[goff + 1]) + adv.y; m1 = fmaxf(m1, NEG_SLOPE * m1);
  float m2 = fdec(gmaxu[goff + 2]) + adv.z; m2 = fmaxf(m2, NEG_SLOPE * m2);
  float m3 = fdec(gmaxu[goff + 3]) + adv.w; m3 = fmaxf(m3, NEG_SLOPE * m3);
  int beg = __builtin_amdgcn_readfirstlane(row_start[node]);
  int end = __builtin_amdgcn_readfirstlane(row_start[node + 1]);
  const unsigned* hw = (const unsigned*)hb;

  float lq = 0.f, cq0 = 0.f, cq1 = 0.f, cq2 = 0.f, cq3 = 0.f;

  for (int cbeg = beg; cbeg < end; cbeg += 64) {
    int cnt = end - cbeg; if (cnt > 64) cnt = 64;
    int eidx = cbeg + (lane < cnt ? lane : cnt - 1);
    int s_l = csr_src[eidx];
    float4 as = *(const float4*)(a_src + (size_t)s_l * 4);
    float v0 = as.x + adv.x; v0 = fmaxf(v0, NEG_SLOPE * v0);
    float v1 = as.y + adv.y; v1 = fmaxf(v1, NEG_SLOPE * v1);
    float v2 = as.z + adv.z; v2 = fmaxf(v2, NEG_SLOPE * v2);
    float v3 = as.w + adv.w; v3 = fmaxf(v3, NEG_SLOPE * v3);
    float p0 = __expf(v0 - m0), p1 = __expf(v1 - m1);
    float p2 = __expf(v2 - m2), p3 = __expf(v3 - m3);
    *(float4*)&plds[wid][lane * 4] = make_float4(p0, p1, p2, p3);
    __builtin_amdgcn_s_waitcnt(0);  // ds_write visible to our ds_reads

    auto step = [&](int jj) {
      int sj = __builtin_amdgcn_readlane(s_l, jj);
      float pq = plds[wid][jj * 4 + qh];
      uint2 d = *(const uint2*)(hw + (size_t)sj * 128 + 2 * lane);
      cq0 += pq * bflo(d.x); cq1 += pq * bfhi(d.x);
      cq2 += pq * bflo(d.y); cq3 += pq * bfhi(d.y);
      lq += pq;
    };
    int j = 0;
    for (; j + 4 <= cnt; j += 4) { step(j); step(j + 1); step(j + 2); step(j + 3); }
    for (; j < cnt; ++j) step(j);
  }

  float4 bq = *(const float4*)(bias + 4 * lane);
  float rq = 1.f / (lq + EPS);
  float o0 = fmaxf(cq0 * rq + bq.x, 0.f);
  float o1 = fmaxf(cq1 * rq + bq.y, 0.f);
  float o2 = fmaxf(cq2 * rq + bq.z, 0.f);
  float o3 = fmaxf(cq3 * rq + bq.w, 0.f);
  uint2 pk;
  pk.x = packbf2(o0, o1);
  pk.y = packbf2(o2, o3);
  *(uint2*)((unsigned*)out + (size_t)node * 128 + 2 * lane) = pk;
}

// ---------------------------------------------------------------------------
extern "C" void kernel_launch(void* const* d_in, const int* in_sizes, int n_in,
                              void* d_out, int out_size, void* d_ws, size_t ws_size,
                              hipStream_t stream) {
  const float* x      = (const float*)d_in[0];
  const int*   ei     = (const int*)d_in[1];
  const float* W1     = (const float*)d_in[2];
  const float* att_s1 = (const float*)d_in[3];
  const float* att_d1 = (const float*)d_in[4];
  const float* b1     = (const float*)d_in[5];
  const float* W2     = (const float*)d_in[6];
  const float* att_s2 = (const float*)d_in[7];
  const float* att_d2 = (const float*)d_in[8];
  const float* b2     = (const float*)d_in[9];
  const float* Wm1    = (const float*)d_in[10];
  const float* bm1    = (const float*)d_in[11];
  const float* Wm2    = (const float*)d_in[12];
  const float* bm2    = (const float*)d_in[13];
  float* out = (float*)d_out;

  int n = in_sizes[0] / 128;   // 50000
  int E = in_sizes[1] / 2;     // 800000
  int Etot = E + n;

  char* ws = (char*)d_ws;
  size_t off = 0;
  auto carve = [&](size_t bytes) {
    char* p = ws + off;
    off += (bytes + 255) & ~(size_t)255;
    return p;
  };
  __hip_bfloat16* hb   = (__hip_bfloat16*)carve((size_t)n * HC * 2);
  __hip_bfloat16* aggb = (__hip_bfloat16*)carve((size_t)n * HC * 2);
  __hip_bfloat16* xb   = (__hip_bfloat16*)carve((size_t)n * 128 * 2);
  __hip_bfloat16* pm1b = (__hip_bfloat16*)carve((size_t)n * HID * 2);
  __hip_bfloat16* W1t  = (__hip_bfloat16*)carve((size_t)128 * HC * 2);
  __hip_bfloat16* W2t  = (__hip_bfloat16*)carve((size_t)HC * HC * 2);
  __hip_bfloat16* Wm1t = (__hip_bfloat16*)carve((size_t)HC * HID * 2);
  __hip_bfloat16* Wm2t = (__hip_bfloat16*)carve((size_t)HID * 121 * 2);
  float* as   = (float*)carve((size_t)n * HEADS * 4);
  float* ad   = (float*)carve((size_t)n * HEADS * 4);
  int*   deg  = (int*)carve((size_t)n * 4);
  int*   row  = (int*)carve((size_t)(n + 1) * 4);
  int*   cur  = (int*)carve((size_t)n * 4);
  int*   csr  = (int*)carve((size_t)Etot * 4);
  int*   bsum = (int*)carve((size_t)1024 * 4);
  unsigned* gmaxu = (unsigned*)carve((size_t)8 * 4);
  (void)ws_size;

  int nb256 = (n + 255) / 256;
  int rows128 = (n + 127) / 128;

  // --- input casts / weight prep ---
  cast_bf16<<<(n * 32 + 255) / 256, 256, 0, stream>>>(x, xb, n * 32);
  prep_weights<<<(122432 + 255) / 256, 256, 0, stream>>>(W1, W2, Wm1, Wm2, W1t, W2t, Wm1t, Wm2t);

  // --- CSR build (+ gmax init) ---
  deg_init<<<nb256, 256, 0, stream>>>(deg, gmaxu, n);
  deg_count<<<(E + 255) / 256, 256, 0, stream>>>(ei, E, deg);
  scan_block<<<nb256, 256, 0, stream>>>(deg, row, bsum, n);
  scan_partials<<<1, 256, 0, stream>>>(bsum, nb256);
  finalize_row<<<nb256, 256, 0, stream>>>(row, bsum, deg, cur, n);
  csr_fill<<<(Etot + 255) / 256, 256, 0, stream>>>(ei, E, n, cur, csr);

  // --- conv1 ---
  mfma_gemm<<<dim3(2, rows128), 256, 0, stream>>>(xb, W1t, nullptr, nullptr, hb, n, HC, 128, 0);
  attn_coef<<<(n * HEADS + 255) / 256, 256, 0, stream>>>(hb, att_s1, att_d1, as, ad, gmaxu, 0, n);
  gat_aggregate<<<(n + 3) / 4, 256, 0, stream>>>(hb, as, ad, row, csr, b1, gmaxu, 0, aggb, n);

  // --- conv2 ---
  mfma_gemm<<<dim3(2, rows128), 256, 0, stream>>>(aggb, W2t, nullptr, nullptr, hb, n, HC, HC, 0);
  attn_coef<<<(n * HEADS + 255) / 256, 256, 0, stream>>>(hb, att_s2, att_d2, as, ad, gmaxu, 4, n);
  gat_aggregate<<<(n + 3) / 4, 256, 0, stream>>>(hb, as, ad, row, csr, b2, gmaxu, 4, aggb, n);

  // --- post_mp ---
  mfma_gemm<<<dim3(1, rows128), 256, 0, stream>>>(aggb, Wm1t, bm1, nullptr, pm1b, n, HID, HC, 0);
  mfma_gemm<<<dim3(1, rows128), 256, 0, stream>>>(pm1b, Wm2t, bm2, out, nullptr, n, 121, HID, 2);
}

// Round 6
// 477.988 us; speedup vs baseline: 1.0937x; 1.0937x over previous
//
#include <hip/hip_runtime.h>
#include <hip/hip_bf16.h>
#include <float.h>

#define HEADS 4
#define HID 64
#define HC 256   // HEADS*HID
#define NEG_SLOPE 0.2f
#define EPS 1e-16f

typedef short bf16x8 __attribute__((ext_vector_type(8)));
typedef float f32x4 __attribute__((ext_vector_type(4)));
typedef unsigned short ushort8 __attribute__((ext_vector_type(8)));

__device__ __forceinline__ float bflo(unsigned u) { return __uint_as_float(u << 16); }
__device__ __forceinline__ float bfhi(unsigned u) { return __uint_as_float(u & 0xffff0000u); }
__device__ __forceinline__ unsigned packbf2(float a, float b) {
  __hip_bfloat16 ha = __float2bfloat16(a), hb = __float2bfloat16(b);
  unsigned short ua = *reinterpret_cast<unsigned short*>(&ha);
  unsigned short ub = *reinterpret_cast<unsigned short*>(&hb);
  return (unsigned)ua | ((unsigned)ub << 16);
}
// monotone float<->uint order-preserving map (for atomicMax on floats)
__device__ __forceinline__ unsigned fenc(float f) {
  unsigned u = __float_as_uint(f);
  return (u & 0x80000000u) ? ~u : (u | 0x80000000u);
}
__device__ __forceinline__ float fdec(unsigned k) {
  unsigned u = (k & 0x80000000u) ? (k ^ 0x80000000u) : ~k;
  return __uint_as_float(u);
}

// ---------------------------------------------------------------------------
// Conv GEMM (R3 padded-LDS structure, known-good): h = A[MxK] @ Bt^T, bf16 out,
// PLUS fused attention-coefficient epilogue:
//   head = 2*blockIdx.x + wn;  a_s[row,head] = <h_row_seg, att_s[head]>,
//   a_d likewise, and per-head global max of a_s via atomicMax (softmax bound).
// ---------------------------------------------------------------------------
#define PK 40  // padded LDS row stride (bf16 elems)

__global__ void __launch_bounds__(256) conv_gemm_attn(
    const __hip_bfloat16* __restrict__ A, const __hip_bfloat16* __restrict__ Bt,
    __hip_bfloat16* __restrict__ Cb,
    const float* __restrict__ att_s, const float* __restrict__ att_d,
    float* __restrict__ a_s, float* __restrict__ a_d,
    unsigned* __restrict__ gmaxu, int goff,
    int M, int N, int K) {
  __shared__ unsigned short As[128 * PK];
  __shared__ unsigned short Bs[128 * PK];
  int tid = threadIdx.x;
  int lane = tid & 63, w = tid >> 6;
  int wm = w & 1, wn = w >> 1;
  int col16 = lane & 15, quad = lane >> 4;
  int row0 = blockIdx.y * 128, col0 = blockIdx.x * 128;
  const unsigned short* Ag = (const unsigned short*)A;
  const unsigned short* Bg = (const unsigned short*)Bt;

  f32x4 acc[4][4] = {};

  for (int k0 = 0; k0 < K; k0 += 32) {
#pragma unroll
    for (int c = tid; c < 512; c += 256) {
      int r = c >> 2, ko = (c & 3) << 3;
      int gr = row0 + r;
      if (gr >= M) gr = M - 1;
      ushort8 v = *(const ushort8*)(Ag + (size_t)gr * K + k0 + ko);
      *(ushort8*)(&As[r * PK + ko]) = v;
    }
#pragma unroll
    for (int c = tid; c < 512; c += 256) {
      int r = c >> 2, ko = (c & 3) << 3;
      int gc = col0 + r;
      if (gc >= N) gc = N - 1;
      ushort8 v = *(const ushort8*)(Bg + (size_t)gc * K + k0 + ko);
      *(ushort8*)(&Bs[r * PK + ko]) = v;
    }
    __syncthreads();
    bf16x8 a[4], b[4];
#pragma unroll
    for (int i = 0; i < 4; i++)
      a[i] = *(const bf16x8*)(&As[(wm * 64 + i * 16 + col16) * PK + quad * 8]);
#pragma unroll
    for (int j = 0; j < 4; j++)
      b[j] = *(const bf16x8*)(&Bs[(wn * 64 + j * 16 + col16) * PK + quad * 8]);
#pragma unroll
    for (int i = 0; i < 4; i++)
#pragma unroll
      for (int j = 0; j < 4; j++)
        acc[i][j] = __builtin_amdgcn_mfma_f32_16x16x32_bf16(a[i], b[j], acc[i][j], 0, 0, 0);
    __syncthreads();
  }

  // ---- h store (bf16) ----
#pragma unroll
  for (int i = 0; i < 4; i++) {
#pragma unroll
    for (int j = 0; j < 4; j++) {
      int gc = col0 + wn * 64 + j * 16 + col16;
      int grb = row0 + wm * 64 + i * 16 + quad * 4;
#pragma unroll
      for (int r = 0; r < 4; r++) {
        int gr = grb + r;
        if (gr < M) Cb[(size_t)gr * N + gc] = __float2bfloat16(acc[i][j][r]);
      }
    }
  }

  // ---- fused attention coefficients ----
  // wave (wm, wn): head = 2*bx + wn, rows wm*64 .. wm*64+63 of this block.
  int head = (blockIdx.x << 1) + wn;
  float ws[4], wd[4];
#pragma unroll
  for (int j = 0; j < 4; j++) {
    ws[j] = att_s[head * HID + j * 16 + col16];
    wd[j] = att_d[head * HID + j * 16 + col16];
  }
  float wavemax = -FLT_MAX;
#pragma unroll
  for (int i = 0; i < 4; i++) {
#pragma unroll
    for (int r = 0; r < 4; r++) {
      float vs = 0.f, vd = 0.f;
#pragma unroll
      for (int j = 0; j < 4; j++) {
        vs += acc[i][j][r] * ws[j];
        vd += acc[i][j][r] * wd[j];
      }
      // reduce across the 16 col16 lanes of this quad group
#pragma unroll
      for (int off = 1; off < 16; off <<= 1) {
        vs += __shfl_xor(vs, off);
        vd += __shfl_xor(vd, off);
      }
      int gr = row0 + wm * 64 + i * 16 + quad * 4 + r;
      if (col16 == 0 && gr < M) {
        a_s[(size_t)gr * 4 + head] = vs;
        a_d[(size_t)gr * 4 + head] = vd;
      }
      wavemax = fmaxf(wavemax, vs);  // rows >= M duplicate row M-1 (clamped staging): harmless
    }
  }
  wavemax = fmaxf(wavemax, __shfl_xor(wavemax, 16));
  wavemax = fmaxf(wavemax, __shfl_xor(wavemax, 32));
  if (lane == 0) atomicMax(&gmaxu[goff + head], fenc(wavemax));
}

// ---------------------------------------------------------------------------
// Fused post_mp: out = sigmoid((aggb@Wm1 + bm1) @ Wm2 + bm2)
// One block = 128 rows. Stage 1: K=256 -> t1[128][64] (bf16, in LDS).
// Stage 2: K=64, N=121 (Wm2t staged in LDS) -> fp32 out with sigmoid.
// ---------------------------------------------------------------------------
#define TS 72  // t1 / W2s LDS row stride (64 + 8)

__global__ void __launch_bounds__(256) postmp_fused(
    const __hip_bfloat16* __restrict__ A, const __hip_bfloat16* __restrict__ Wm1t,
    const __hip_bfloat16* __restrict__ Wm2t, const float* __restrict__ bm1,
    const float* __restrict__ bm2, float* __restrict__ out, int M) {
  __shared__ unsigned short As[128 * PK];
  __shared__ unsigned short Bs[64 * PK];
  __shared__ unsigned short T[128 * TS];
  __shared__ unsigned short W2s[128 * TS];
  int tid = threadIdx.x;
  int lane = tid & 63, w = tid >> 6;
  int col16 = lane & 15, quad = lane >> 4;
  int row0 = blockIdx.x * 128;
  const unsigned short* Ag = (const unsigned short*)A;
  const unsigned short* Bg = (const unsigned short*)Wm1t;
  const unsigned short* W2g = (const unsigned short*)Wm2t;

  // stage Wm2t [121][64] -> W2s (zero-pad rows 121..127)
#pragma unroll
  for (int c = tid; c < 1024; c += 256) {
    int r = c >> 3, ko = (c & 7) << 3;
    ushort8 v = {};
    if (r < 121) v = *(const ushort8*)(W2g + (size_t)r * 64 + ko);
    *(ushort8*)(&W2s[r * TS + ko]) = v;
  }

  // ---- stage 1: t1 = A@Wm1 + bm1 ; wave w -> rows w*32..w*32+31, cols 0..63
  f32x4 acc1[2][4] = {};
  for (int k0 = 0; k0 < 256; k0 += 32) {
#pragma unroll
    for (int c = tid; c < 512; c += 256) {
      int r = c >> 2, ko = (c & 3) << 3;
      int gr = row0 + r;
      if (gr >= M) gr = M - 1;
      ushort8 v = *(const ushort8*)(Ag + (size_t)gr * 256 + k0 + ko);
      *(ushort8*)(&As[r * PK + ko]) = v;
    }
    {
      int r = tid >> 2, ko = (tid & 3) << 3;  // 64 rows x 4 granules = 256 chunks
      ushort8 v = *(const ushort8*)(Bg + (size_t)r * 256 + k0 + ko);
      *(ushort8*)(&Bs[r * PK + ko]) = v;
    }
    __syncthreads();
    bf16x8 a[2], b[4];
#pragma unroll
    for (int i = 0; i < 2; i++)
      a[i] = *(const bf16x8*)(&As[(w * 32 + i * 16 + col16) * PK + quad * 8]);
#pragma unroll
    for (int j = 0; j < 4; j++)
      b[j] = *(const bf16x8*)(&Bs[(j * 16 + col16) * PK + quad * 8]);
#pragma unroll
    for (int i = 0; i < 2; i++)
#pragma unroll
      for (int j = 0; j < 4; j++)
        acc1[i][j] = __builtin_amdgcn_mfma_f32_16x16x32_bf16(a[i], b[j], acc1[i][j], 0, 0, 0);
    __syncthreads();
  }
  // t1 -> LDS (bf16), +bm1
#pragma unroll
  for (int i = 0; i < 2; i++) {
#pragma unroll
    for (int j = 0; j < 4; j++) {
      int col = j * 16 + col16;
      float bv = bm1[col];
#pragma unroll
      for (int r = 0; r < 4; r++) {
        int rl = w * 32 + i * 16 + quad * 4 + r;
        __hip_bfloat16 hv = __float2bfloat16(acc1[i][j][r] + bv);
        T[rl * TS + col] = *reinterpret_cast<unsigned short*>(&hv);
      }
    }
  }
  __syncthreads();

  // ---- stage 2: out = sigmoid(t1 @ Wm2 + bm2); wave (wm2, wn2) 64x64
  int wm2 = w & 1, wn2 = w >> 1;
  f32x4 acc2[4][4] = {};
#pragma unroll
  for (int kk = 0; kk < 2; kk++) {
    bf16x8 a[4], b[4];
#pragma unroll
    for (int i = 0; i < 4; i++)
      a[i] = *(const bf16x8*)(&T[(wm2 * 64 + i * 16 + col16) * TS + kk * 32 + quad * 8]);
#pragma unroll
    for (int j = 0; j < 4; j++)
      b[j] = *(const bf16x8*)(&W2s[(wn2 * 64 + j * 16 + col16) * TS + kk * 32 + quad * 8]);
#pragma unroll
    for (int i = 0; i < 4; i++)
#pragma unroll
      for (int j = 0; j < 4; j++)
        acc2[i][j] = __builtin_amdgcn_mfma_f32_16x16x32_bf16(a[i], b[j], acc2[i][j], 0, 0, 0);
  }
#pragma unroll
  for (int i = 0; i < 4; i++) {
#pragma unroll
    for (int j = 0; j < 4; j++) {
      int gc = wn2 * 64 + j * 16 + col16;
      if (gc >= 121) continue;
      float bv = bm2[gc];
      int grb = row0 + wm2 * 64 + i * 16 + quad * 4;
#pragma unroll
      for (int r = 0; r < 4; r++) {
        int gr = grb + r;
        if (gr >= M) continue;
        float v = acc2[i][j][r] + bv;
        out[(size_t)gr * 121 + gc] = 1.f / (1.f + __expf(-v));
      }
    }
  }
}

// ---------------------------------------------------------------------------
// casts / weight prep
// ---------------------------------------------------------------------------
__global__ void cast_bf16(const float* __restrict__ src, __hip_bfloat16* __restrict__ dst, int count4) {
  int i = blockIdx.x * 256 + threadIdx.x;
  if (i >= count4) return;
  float4 v = *(const float4*)(src + 4 * (size_t)i);
  uint2 pk;
  pk.x = packbf2(v.x, v.y);
  pk.y = packbf2(v.z, v.w);
  *(uint2*)((unsigned*)dst + 2 * (size_t)i) = pk;
}

__global__ void prep_weights(const float* __restrict__ W1, const float* __restrict__ W2,
                             const float* __restrict__ Wm1, const float* __restrict__ Wm2,
                             __hip_bfloat16* __restrict__ W1t, __hip_bfloat16* __restrict__ W2t,
                             __hip_bfloat16* __restrict__ Wm1t, __hip_bfloat16* __restrict__ Wm2t) {
  int i = blockIdx.x * 256 + threadIdx.x;
  if (i < 128 * 256) {  // W1: K=128, N=256
    int nn = i / 128, kk = i - nn * 128;
    W1t[i] = __float2bfloat16(W1[(size_t)kk * 256 + nn]);
    return;
  }
  i -= 128 * 256;
  if (i < 256 * 256) {  // W2
    int nn = i / 256, kk = i - nn * 256;
    W2t[i] = __float2bfloat16(W2[(size_t)kk * 256 + nn]);
    return;
  }
  i -= 256 * 256;
  if (i < 256 * 64) {   // Wm1: K=256, N=64
    int nn = i / 256, kk = i - nn * 256;
    Wm1t[i] = __float2bfloat16(Wm1[(size_t)kk * 64 + nn]);
    return;
  }
  i -= 256 * 64;
  if (i < 64 * 121) {   // Wm2: K=64, N=121
    int nn = i / 64, kk = i - nn * 64;
    Wm2t[i] = __float2bfloat16(Wm2[(size_t)kk * 121 + nn]);
  }
}

// ---------------------------------------------------------------------------
// CSR build
// ---------------------------------------------------------------------------
__global__ void deg_init(int* __restrict__ deg, unsigned* __restrict__ gmaxu, int n) {
  int i = blockIdx.x * 256 + threadIdx.x;
  if (i < n) deg[i] = 1;
  if (i < 8) gmaxu[i] = 0u;
}

__global__ void deg_count(const int* __restrict__ ei, int E, int* __restrict__ deg) {
  int i = blockIdx.x * 256 + threadIdx.x;
  if (i < E) atomicAdd(&deg[ei[E + i]], 1);
}

__global__ void __launch_bounds__(256) scan_block(const int* __restrict__ deg,
                                                  int* __restrict__ row_start,
                                                  int* __restrict__ bsum, int n) {
  __shared__ int wt[4];
  int tid = threadIdx.x, lane = tid & 63, w = tid >> 6;
  int i = blockIdx.x * 256 + tid;
  int v = (i < n) ? deg[i] : 0;
  int s = v;
#pragma unroll
  for (int off = 1; off < 64; off <<= 1) {
    int t = __shfl_up(s, off);
    if (lane >= off) s += t;
  }
  if (lane == 63) wt[w] = s;
  __syncthreads();
  int add = 0;
  if (w > 0) add += wt[0];
  if (w > 1) add += wt[1];
  if (w > 2) add += wt[2];
  if (i < n) row_start[i + 1] = s + add;
  if (tid == 0) bsum[blockIdx.x] = wt[0] + wt[1] + wt[2] + wt[3];
}

__global__ void __launch_bounds__(256) scan_partials(int* __restrict__ bsum, int nb) {
  __shared__ int wt[4];
  int tid = threadIdx.x, lane = tid & 63, w = tid >> 6;
  int v = (tid < nb) ? bsum[tid] : 0;
  int s = v;
#pragma unroll
  for (int off = 1; off < 64; off <<= 1) {
    int t = __shfl_up(s, off);
    if (lane >= off) s += t;
  }
  if (lane == 63) wt[w] = s;
  __syncthreads();
  int add = 0;
  if (w > 0) add += wt[0];
  if (w > 1) add += wt[1];
  if (w > 2) add += wt[2];
  if (tid < nb) bsum[tid] = s + add - v;
}

__global__ void finalize_row(int* __restrict__ row_start, const int* __restrict__ bsum_ex,
                             const int* __restrict__ deg, int* __restrict__ cur, int n) {
  int i = blockIdx.x * 256 + threadIdx.x;
  if (i == 0) row_start[0] = 0;
  if (i < n) {
    int v = row_start[i + 1] + bsum_ex[blockIdx.x];
    row_start[i + 1] = v;
    cur[i] = v - deg[i];
  }
}

__global__ void csr_fill(const int* __restrict__ ei, int E, int n,
                         int* __restrict__ cur, int* __restrict__ csr_src) {
  int i = blockIdx.x * 256 + threadIdx.x;
  int Etot = E + n;
  if (i >= Etot) return;
  int s, d;
  if (i < E) { s = ei[i]; d = ei[E + i]; }
  else { s = d = i - E; }
  int pos = atomicAdd(&cur[d], 1);
  csr_src[pos] = s;
}

// ---------------------------------------------------------------------------
// GAT aggregation, single pass (softmax shift = per-head global upper bound;
// shift-invariance makes this exact). Proven memory-stream-bound at 64.5 us.
// ---------------------------------------------------------------------------
__global__ void __launch_bounds__(256) gat_aggregate(
    const __hip_bfloat16* __restrict__ hb, const float* __restrict__ a_src,
    const float* __restrict__ a_dst, const int* __restrict__ row_start,
    const int* __restrict__ csr_src, const float* __restrict__ bias,
    const unsigned* __restrict__ gmaxu, int goff,
    __hip_bfloat16* __restrict__ out, int n) {
  __shared__ float plds[4][256];
  int wid = threadIdx.x >> 6;
  int lane = threadIdx.x & 63;
  int qh = lane >> 4;
  int node = (blockIdx.x << 2) + wid;
  if (node >= n) return;
  float4 adv = *(const float4*)(a_dst + (size_t)node * 4);
  float m0 = fdec(gmaxu[goff + 0]) + adv.x; m0 = fmaxf(m0, NEG_SLOPE * m0);
  float m1 = fdec(gmaxu[goff + 1]) + adv.y; m1 = fmaxf(m1, NEG_SLOPE * m1);
  float m2 = fdec(gmaxu[goff + 2]) + adv.z; m2 = fmaxf(m2, NEG_SLOPE * m2);
  float m3 = fdec(gmaxu[goff + 3]) + adv.w; m3 = fmaxf(m3, NEG_SLOPE * m3);
  int beg = __builtin_amdgcn_readfirstlane(row_start[node]);
  int end = __builtin_amdgcn_readfirstlane(row_start[node + 1]);
  const unsigned* hw = (const unsigned*)hb;

  float lq = 0.f, cq0 = 0.f, cq1 = 0.f, cq2 = 0.f, cq3 = 0.f;

  for (int cbeg = beg; cbeg < end; cbeg += 64) {
    int cnt = end - cbeg; if (cnt > 64) cnt = 64;
    int eidx = cbeg + (lane < cnt ? lane : cnt - 1);
    int s_l = csr_src[eidx];
    float4 as = *(const float4*)(a_src + (size_t)s_l * 4);
    float v0 = as.x + adv.x; v0 = fmaxf(v0, NEG_SLOPE * v0);
    float v1 = as.y + adv.y; v1 = fmaxf(v1, NEG_SLOPE * v1);
    float v2 = as.z + adv.z; v2 = fmaxf(v2, NEG_SLOPE * v2);
    float v3 = as.w + adv.w; v3 = fmaxf(v3, NEG_SLOPE * v3);
    float p0 = __expf(v0 - m0), p1 = __expf(v1 - m1);
    float p2 = __expf(v2 - m2), p3 = __expf(v3 - m3);
    *(float4*)&plds[wid][lane * 4] = make_float4(p0, p1, p2, p3);
    __builtin_amdgcn_s_waitcnt(0);

    auto step = [&](int jj) {
      int sj = __builtin_amdgcn_readlane(s_l, jj);
      float pq = plds[wid][jj * 4 + qh];
      uint2 d = *(const uint2*)(hw + (size_t)sj * 128 + 2 * lane);
      cq0 += pq * bflo(d.x); cq1 += pq * bfhi(d.x);
      cq2 += pq * bflo(d.y); cq3 += pq * bfhi(d.y);
      lq += pq;
    };
    int j = 0;
    for (; j + 4 <= cnt; j += 4) { step(j); step(j + 1); step(j + 2); step(j + 3); }
    for (; j < cnt; ++j) step(j);
  }

  float4 bq = *(const float4*)(bias + 4 * lane);
  float rq = 1.f / (lq + EPS);
  float o0 = fmaxf(cq0 * rq + bq.x, 0.f);
  float o1 = fmaxf(cq1 * rq + bq.y, 0.f);
  float o2 = fmaxf(cq2 * rq + bq.z, 0.f);
  float o3 = fmaxf(cq3 * rq + bq.w, 0.f);
  uint2 pk;
  pk.x = packbf2(o0, o1);
  pk.y = packbf2(o2, o3);
  *(uint2*)((unsigned*)out + (size_t)node * 128 + 2 * lane) = pk;
}

// ---------------------------------------------------------------------------
extern "C" void kernel_launch(void* const* d_in, const int* in_sizes, int n_in,
                              void* d_out, int out_size, void* d_ws, size_t ws_size,
                              hipStream_t stream) {
  const float* x      = (const float*)d_in[0];
  const int*   ei     = (const int*)d_in[1];
  const float* W1     = (const float*)d_in[2];
  const float* att_s1 = (const float*)d_in[3];
  const float* att_d1 = (const float*)d_in[4];
  const float* b1     = (const float*)d_in[5];
  const float* W2     = (const float*)d_in[6];
  const float* att_s2 = (const float*)d_in[7];
  const float* att_d2 = (const float*)d_in[8];
  const float* b2     = (const float*)d_in[9];
  const float* Wm1    = (const float*)d_in[10];
  const float* bm1    = (const float*)d_in[11];
  const float* Wm2    = (const float*)d_in[12];
  const float* bm2    = (const float*)d_in[13];
  float* out = (float*)d_out;

  int n = in_sizes[0] / 128;   // 50000
  int E = in_sizes[1] / 2;     // 800000
  int Etot = E + n;

  char* ws = (char*)d_ws;
  size_t off = 0;
  auto carve = [&](size_t bytes) {
    char* p = ws + off;
    off += (bytes + 255) & ~(size_t)255;
    return p;
  };
  __hip_bfloat16* hb   = (__hip_bfloat16*)carve((size_t)n * HC * 2);
  __hip_bfloat16* aggb = (__hip_bfloat16*)carve((size_t)n * HC * 2);
  __hip_bfloat16* xb   = (__hip_bfloat16*)carve((size_t)n * 128 * 2);
  __hip_bfloat16* W1t  = (__hip_bfloat16*)carve((size_t)128 * HC * 2);
  __hip_bfloat16* W2t  = (__hip_bfloat16*)carve((size_t)HC * HC * 2);
  __hip_bfloat16* Wm1t = (__hip_bfloat16*)carve((size_t)HC * HID * 2);
  __hip_bfloat16* Wm2t = (__hip_bfloat16*)carve((size_t)HID * 121 * 2);
  float* as   = (float*)carve((size_t)n * HEADS * 4);
  float* ad   = (float*)carve((size_t)n * HEADS * 4);
  int*   deg  = (int*)carve((size_t)n * 4);
  int*   row  = (int*)carve((size_t)(n + 1) * 4);
  int*   cur  = (int*)carve((size_t)n * 4);
  int*   csr  = (int*)carve((size_t)Etot * 4);
  int*   bsum = (int*)carve((size_t)1024 * 4);
  unsigned* gmaxu = (unsigned*)carve((size_t)8 * 4);
  (void)ws_size;

  int nb256 = (n + 255) / 256;
  int rows128 = (n + 127) / 128;

  // --- input casts / weight prep ---
  cast_bf16<<<(n * 32 + 255) / 256, 256, 0, stream>>>(x, xb, n * 32);
  prep_weights<<<(122432 + 255) / 256, 256, 0, stream>>>(W1, W2, Wm1, Wm2, W1t, W2t, Wm1t, Wm2t);

  // --- CSR build (+ gmax init) ---
  deg_init<<<nb256, 256, 0, stream>>>(deg, gmaxu, n);
  deg_count<<<(E + 255) / 256, 256, 0, stream>>>(ei, E, deg);
  scan_block<<<nb256, 256, 0, stream>>>(deg, row, bsum, n);
  scan_partials<<<1, 256, 0, stream>>>(bsum, nb256);
  finalize_row<<<nb256, 256, 0, stream>>>(row, bsum, deg, cur, n);
  csr_fill<<<(Etot + 255) / 256, 256, 0, stream>>>(ei, E, n, cur, csr);

  // --- conv1 (GEMM + fused attn coefs) ---
  conv_gemm_attn<<<dim3(2, rows128), 256, 0, stream>>>(
      xb, W1t, hb, att_s1, att_d1, as, ad, gmaxu, 0, n, HC, 128);
  gat_aggregate<<<(n + 3) / 4, 256, 0, stream>>>(hb, as, ad, row, csr, b1, gmaxu, 0, aggb, n);

  // --- conv2 ---
  conv_gemm_attn<<<dim3(2, rows128), 256, 0, stream>>>(
      aggb, W2t, hb, att_s2, att_d2, as, ad, gmaxu, 4, n, HC, HC);
  gat_aggregate<<<(n + 3) / 4, 256, 0, stream>>>(hb, as, ad, row, csr, b2, gmaxu, 4, aggb, n);

  // --- post_mp (fused 256->64->121 + sigmoid) ---
  postmp_fused<<<rows128, 256, 0, stream>>>(aggb, Wm1t, Wm2t, bm1, bm2, out, n);
}

// Round 7
// 407.692 us; speedup vs baseline: 1.2823x; 1.1724x over previous
//
#include <hip/hip_runtime.h>
#include <hip/hip_bf16.h>
#include <float.h>

#define HEADS 4
#define HID 64
#define HC 256   // HEADS*HID
#define NEG_SLOPE 0.2f
#define EPS 1e-16f

typedef short bf16x8 __attribute__((ext_vector_type(8)));
typedef float f32x4 __attribute__((ext_vector_type(4)));
typedef unsigned short ushort8 __attribute__((ext_vector_type(8)));

__device__ __forceinline__ float bflo(unsigned u) { return __uint_as_float(u << 16); }
__device__ __forceinline__ float bfhi(unsigned u) { return __uint_as_float(u & 0xffff0000u); }
__device__ __forceinline__ unsigned packbf2(float a, float b) {
  __hip_bfloat16 ha = __float2bfloat16(a), hb = __float2bfloat16(b);
  unsigned short ua = *reinterpret_cast<unsigned short*>(&ha);
  unsigned short ub = *reinterpret_cast<unsigned short*>(&hb);
  return (unsigned)ua | ((unsigned)ub << 16);
}

#define PK 40  // padded LDS row stride (bf16 elems) — proven conflict-light

// ---------------------------------------------------------------------------
// Conv GEMM, latency-tolerant rebuild: 64 rows x 256 cols per block (N=256
// fixed), 782 blocks, double-buffered LDS with VGPR prefetch (1 barrier/iter).
// Wave w computes cols 64w..64w+63 == head w. Fused epilogue: bf16 h store,
// a_s/a_d per (row, head=w), per-block per-head max via plain store (no
// atomics; reduced by reduce_gmax).
// ---------------------------------------------------------------------------
__global__ void __launch_bounds__(256) conv_gemm_attn(
    const __hip_bfloat16* __restrict__ A, const __hip_bfloat16* __restrict__ Bt,
    __hip_bfloat16* __restrict__ Cb,
    const float* __restrict__ att_s, const float* __restrict__ att_d,
    float* __restrict__ a_s, float* __restrict__ a_d,
    float* __restrict__ blockmax, int M, int K) {
  __shared__ unsigned short As[2][64 * PK];
  __shared__ unsigned short Bs[2][256 * PK];
  int tid = threadIdx.x;
  int lane = tid & 63, w = tid >> 6;
  int col16 = lane & 15, quad = lane >> 4;
  int row0 = blockIdx.x * 64;
  const unsigned short* Ag = (const unsigned short*)A;
  const unsigned short* Bg = (const unsigned short*)Bt;

  // staging map: A tile 64x32 = 256 granules (1/thread); B tile 256x32 = 1024 (4/thread)
  int ar = tid >> 2;
  int ako = (tid & 3) << 3;
  int agr = row0 + ar; if (agr >= M) agr = M - 1;
  const unsigned short* aga = Ag + (size_t)agr * K + ako;

  f32x4 acc[4][4] = {};
  int niter = K >> 5;

  ushort8 pa, pb[4];
  // ---- preload tile 0 -> buf 0 ----
  pa = *(const ushort8*)(aga);
#pragma unroll
  for (int p = 0; p < 4; p++) {
    int i2 = tid + (p << 8);
    int br = i2 >> 2, bko = (i2 & 3) << 3;
    pb[p] = *(const ushort8*)(Bg + (size_t)br * K + bko);
  }
  *(ushort8*)(&As[0][ar * PK + ako]) = pa;
#pragma unroll
  for (int p = 0; p < 4; p++) {
    int i2 = tid + (p << 8);
    int br = i2 >> 2, bko = (i2 & 3) << 3;
    *(ushort8*)(&Bs[0][br * PK + bko]) = pb[p];
  }
  __syncthreads();

  for (int it = 0; it < niter; ++it) {
    int cur = it & 1, nxt = cur ^ 1;
    int k1 = (it + 1) << 5;
    if (it + 1 < niter) {  // issue prefetch (no wait here)
      pa = *(const ushort8*)(aga + k1);
#pragma unroll
      for (int p = 0; p < 4; p++) {
        int i2 = tid + (p << 8);
        int br = i2 >> 2, bko = (i2 & 3) << 3;
        pb[p] = *(const ushort8*)(Bg + (size_t)br * K + k1 + bko);
      }
    }
    bf16x8 a[4], b[4];
#pragma unroll
    for (int i = 0; i < 4; i++)
      a[i] = *(const bf16x8*)(&As[cur][(i * 16 + col16) * PK + quad * 8]);
#pragma unroll
    for (int j = 0; j < 4; j++)
      b[j] = *(const bf16x8*)(&Bs[cur][((w << 6) + j * 16 + col16) * PK + quad * 8]);
#pragma unroll
    for (int i = 0; i < 4; i++)
#pragma unroll
      for (int j = 0; j < 4; j++)
        acc[i][j] = __builtin_amdgcn_mfma_f32_16x16x32_bf16(a[i], b[j], acc[i][j], 0, 0, 0);
    if (it + 1 < niter) {  // commit prefetch to other buffer (vmcnt wait lands here)
      *(ushort8*)(&As[nxt][ar * PK + ako]) = pa;
#pragma unroll
      for (int p = 0; p < 4; p++) {
        int i2 = tid + (p << 8);
        int br = i2 >> 2, bko = (i2 & 3) << 3;
        *(ushort8*)(&Bs[nxt][br * PK + bko]) = pb[p];
      }
    }
    __syncthreads();
  }

  // ---- h store (bf16) ----
#pragma unroll
  for (int i = 0; i < 4; i++) {
#pragma unroll
    for (int j = 0; j < 4; j++) {
      int gc = (w << 6) + j * 16 + col16;
      int grb = row0 + i * 16 + quad * 4;
#pragma unroll
      for (int r = 0; r < 4; r++) {
        int gr = grb + r;
        if (gr < M) Cb[(size_t)gr * 256 + gc] = __float2bfloat16(acc[i][j][r]);
      }
    }
  }

  // ---- fused attention coefficients (head = w) ----
  float ws4[4], wd4[4];
#pragma unroll
  for (int j = 0; j < 4; j++) {
    ws4[j] = att_s[(w << 6) + j * 16 + col16];
    wd4[j] = att_d[(w << 6) + j * 16 + col16];
  }
  float wavemax = -FLT_MAX;
#pragma unroll
  for (int i = 0; i < 4; i++) {
#pragma unroll
    for (int r = 0; r < 4; r++) {
      float vs = 0.f, vd = 0.f;
#pragma unroll
      for (int j = 0; j < 4; j++) {
        vs += acc[i][j][r] * ws4[j];
        vd += acc[i][j][r] * wd4[j];
      }
#pragma unroll
      for (int off = 1; off < 16; off <<= 1) {
        vs += __shfl_xor(vs, off);
        vd += __shfl_xor(vd, off);
      }
      int gr = row0 + i * 16 + quad * 4 + r;
      if (col16 == 0 && gr < M) {
        a_s[(size_t)gr * 4 + w] = vs;
        a_d[(size_t)gr * 4 + w] = vd;
      }
      wavemax = fmaxf(wavemax, vs);  // clamped dup rows repeat row M-1: harmless for max
    }
  }
  wavemax = fmaxf(wavemax, __shfl_xor(wavemax, 16));
  wavemax = fmaxf(wavemax, __shfl_xor(wavemax, 32));
  if (lane == 0) blockmax[(size_t)blockIdx.x * 4 + w] = wavemax;
}

// reduce blockmax[nb][4] -> gmaxf[goff+0..3]
__global__ void __launch_bounds__(256) reduce_gmax(const float* __restrict__ blockmax,
                                                   float* __restrict__ gmaxf, int goff, int nb) {
  __shared__ float wm[4][4];
  int tid = threadIdx.x, lane = tid & 63, w = tid >> 6;
  int hd = tid & 3;
  float m = -FLT_MAX;
  for (int i = tid >> 2; i < nb; i += 64)
    m = fmaxf(m, blockmax[(size_t)i * 4 + hd]);
#pragma unroll
  for (int off = 4; off < 64; off <<= 1)
    m = fmaxf(m, __shfl_xor(m, off));
  if (lane < 4) wm[w][lane] = m;
  __syncthreads();
  if (tid < 4) {
    float r = fmaxf(fmaxf(wm[0][tid], wm[1][tid]), fmaxf(wm[2][tid], wm[3][tid]));
    gmaxf[goff + tid] = r;
  }
}

// ---------------------------------------------------------------------------
// Fused post_mp: out = sigmoid((aggb@Wm1 + bm1) @ Wm2 + bm2)  (unchanged R5)
// ---------------------------------------------------------------------------
#define TS 72

__global__ void __launch_bounds__(256) postmp_fused(
    const __hip_bfloat16* __restrict__ A, const __hip_bfloat16* __restrict__ Wm1t,
    const __hip_bfloat16* __restrict__ Wm2t, const float* __restrict__ bm1,
    const float* __restrict__ bm2, float* __restrict__ out, int M) {
  __shared__ unsigned short As[128 * PK];
  __shared__ unsigned short Bs[64 * PK];
  __shared__ unsigned short T[128 * TS];
  __shared__ unsigned short W2s[128 * TS];
  int tid = threadIdx.x;
  int lane = tid & 63, w = tid >> 6;
  int col16 = lane & 15, quad = lane >> 4;
  int row0 = blockIdx.x * 128;
  const unsigned short* Ag = (const unsigned short*)A;
  const unsigned short* Bg = (const unsigned short*)Wm1t;
  const unsigned short* W2g = (const unsigned short*)Wm2t;

#pragma unroll
  for (int c = tid; c < 1024; c += 256) {
    int r = c >> 3, ko = (c & 7) << 3;
    ushort8 v = {};
    if (r < 121) v = *(const ushort8*)(W2g + (size_t)r * 64 + ko);
    *(ushort8*)(&W2s[r * TS + ko]) = v;
  }

  f32x4 acc1[2][4] = {};
  for (int k0 = 0; k0 < 256; k0 += 32) {
#pragma unroll
    for (int c = tid; c < 512; c += 256) {
      int r = c >> 2, ko = (c & 3) << 3;
      int gr = row0 + r;
      if (gr >= M) gr = M - 1;
      ushort8 v = *(const ushort8*)(Ag + (size_t)gr * 256 + k0 + ko);
      *(ushort8*)(&As[r * PK + ko]) = v;
    }
    {
      int r = tid >> 2, ko = (tid & 3) << 3;
      ushort8 v = *(const ushort8*)(Bg + (size_t)r * 256 + k0 + ko);
      *(ushort8*)(&Bs[r * PK + ko]) = v;
    }
    __syncthreads();
    bf16x8 a[2], b[4];
#pragma unroll
    for (int i = 0; i < 2; i++)
      a[i] = *(const bf16x8*)(&As[(w * 32 + i * 16 + col16) * PK + quad * 8]);
#pragma unroll
    for (int j = 0; j < 4; j++)
      b[j] = *(const bf16x8*)(&Bs[(j * 16 + col16) * PK + quad * 8]);
#pragma unroll
    for (int i = 0; i < 2; i++)
#pragma unroll
      for (int j = 0; j < 4; j++)
        acc1[i][j] = __builtin_amdgcn_mfma_f32_16x16x32_bf16(a[i], b[j], acc1[i][j], 0, 0, 0);
    __syncthreads();
  }
#pragma unroll
  for (int i = 0; i < 2; i++) {
#pragma unroll
    for (int j = 0; j < 4; j++) {
      int col = j * 16 + col16;
      float bv = bm1[col];
#pragma unroll
      for (int r = 0; r < 4; r++) {
        int rl = w * 32 + i * 16 + quad * 4 + r;
        __hip_bfloat16 hv = __float2bfloat16(acc1[i][j][r] + bv);
        T[rl * TS + col] = *reinterpret_cast<unsigned short*>(&hv);
      }
    }
  }
  __syncthreads();

  int wm2 = w & 1, wn2 = w >> 1;
  f32x4 acc2[4][4] = {};
#pragma unroll
  for (int kk = 0; kk < 2; kk++) {
    bf16x8 a[4], b[4];
#pragma unroll
    for (int i = 0; i < 4; i++)
      a[i] = *(const bf16x8*)(&T[(wm2 * 64 + i * 16 + col16) * TS + kk * 32 + quad * 8]);
#pragma unroll
    for (int j = 0; j < 4; j++)
      b[j] = *(const bf16x8*)(&W2s[(wn2 * 64 + j * 16 + col16) * TS + kk * 32 + quad * 8]);
#pragma unroll
    for (int i = 0; i < 4; i++)
#pragma unroll
      for (int j = 0; j < 4; j++)
        acc2[i][j] = __builtin_amdgcn_mfma_f32_16x16x32_bf16(a[i], b[j], acc2[i][j], 0, 0, 0);
  }
#pragma unroll
  for (int i = 0; i < 4; i++) {
#pragma unroll
    for (int j = 0; j < 4; j++) {
      int gc = wn2 * 64 + j * 16 + col16;
      if (gc >= 121) continue;
      float bv = bm2[gc];
      int grb = row0 + wm2 * 64 + i * 16 + quad * 4;
#pragma unroll
      for (int r = 0; r < 4; r++) {
        int gr = grb + r;
        if (gr >= M) continue;
        float v = acc2[i][j][r] + bv;
        out[(size_t)gr * 121 + gc] = 1.f / (1.f + __expf(-v));
      }
    }
  }
}

// ---------------------------------------------------------------------------
// casts / weight prep
// ---------------------------------------------------------------------------
__global__ void cast_bf16(const float* __restrict__ src, __hip_bfloat16* __restrict__ dst, int count4) {
  int i = blockIdx.x * 256 + threadIdx.x;
  if (i >= count4) return;
  float4 v = *(const float4*)(src + 4 * (size_t)i);
  uint2 pk;
  pk.x = packbf2(v.x, v.y);
  pk.y = packbf2(v.z, v.w);
  *(uint2*)((unsigned*)dst + 2 * (size_t)i) = pk;
}

__global__ void prep_weights(const float* __restrict__ W1, const float* __restrict__ W2,
                             const float* __restrict__ Wm1, const float* __restrict__ Wm2,
                             __hip_bfloat16* __restrict__ W1t, __hip_bfloat16* __restrict__ W2t,
                             __hip_bfloat16* __restrict__ Wm1t, __hip_bfloat16* __restrict__ Wm2t) {
  int i = blockIdx.x * 256 + threadIdx.x;
  if (i < 128 * 256) {
    int nn = i / 128, kk = i - nn * 128;
    W1t[i] = __float2bfloat16(W1[(size_t)kk * 256 + nn]);
    return;
  }
  i -= 128 * 256;
  if (i < 256 * 256) {
    int nn = i / 256, kk = i - nn * 256;
    W2t[i] = __float2bfloat16(W2[(size_t)kk * 256 + nn]);
    return;
  }
  i -= 256 * 256;
  if (i < 256 * 64) {
    int nn = i / 256, kk = i - nn * 256;
    Wm1t[i] = __float2bfloat16(Wm1[(size_t)kk * 64 + nn]);
    return;
  }
  i -= 256 * 64;
  if (i < 64 * 121) {
    int nn = i / 64, kk = i - nn * 64;
    Wm2t[i] = __float2bfloat16(Wm2[(size_t)kk * 121 + nn]);
  }
}

// ---------------------------------------------------------------------------
// CSR build
// ---------------------------------------------------------------------------
__global__ void deg_init(int* __restrict__ deg, int n) {
  int i = blockIdx.x * 256 + threadIdx.x;
  if (i < n) deg[i] = 1;
}

__global__ void deg_count(const int* __restrict__ ei, int E, int* __restrict__ deg) {
  int i = blockIdx.x * 256 + threadIdx.x;
  if (i < E) atomicAdd(&deg[ei[E + i]], 1);
}

__global__ void __launch_bounds__(256) scan_block(const int* __restrict__ deg,
                                                  int* __restrict__ row_start,
                                                  int* __restrict__ bsum, int n) {
  __shared__ int wt[4];
  int tid = threadIdx.x, lane = tid & 63, w = tid >> 6;
  int i = blockIdx.x * 256 + tid;
  int v = (i < n) ? deg[i] : 0;
  int s = v;
#pragma unroll
  for (int off = 1; off < 64; off <<= 1) {
    int t = __shfl_up(s, off);
    if (lane >= off) s += t;
  }
  if (lane == 63) wt[w] = s;
  __syncthreads();
  int add = 0;
  if (w > 0) add += wt[0];
  if (w > 1) add += wt[1];
  if (w > 2) add += wt[2];
  if (i < n) row_start[i + 1] = s + add;
  if (tid == 0) bsum[blockIdx.x] = wt[0] + wt[1] + wt[2] + wt[3];
}

__global__ void __launch_bounds__(256) scan_partials(int* __restrict__ bsum, int nb) {
  __shared__ int wt[4];
  int tid = threadIdx.x, lane = tid & 63, w = tid >> 6;
  int v = (tid < nb) ? bsum[tid] : 0;
  int s = v;
#pragma unroll
  for (int off = 1; off < 64; off <<= 1) {
    int t = __shfl_up(s, off);
    if (lane >= off) s += t;
  }
  if (lane == 63) wt[w] = s;
  __syncthreads();
  int add = 0;
  if (w > 0) add += wt[0];
  if (w > 1) add += wt[1];
  if (w > 2) add += wt[2];
  if (tid < nb) bsum[tid] = s + add - v;
}

__global__ void finalize_row(int* __restrict__ row_start, const int* __restrict__ bsum_ex,
                             const int* __restrict__ deg, int* __restrict__ cur, int n) {
  int i = blockIdx.x * 256 + threadIdx.x;
  if (i == 0) row_start[0] = 0;
  if (i < n) {
    int v = row_start[i + 1] + bsum_ex[blockIdx.x];
    row_start[i + 1] = v;
    cur[i] = v - deg[i];
  }
}

__global__ void csr_fill(const int* __restrict__ ei, int E, int n,
                         int* __restrict__ cur, int* __restrict__ csr_src) {
  int i = blockIdx.x * 256 + threadIdx.x;
  int Etot = E + n;
  if (i >= Etot) return;
  int s, d;
  if (i < E) { s = ei[i]; d = ei[E + i]; }
  else { s = d = i - E; }
  int pos = atomicAdd(&cur[d], 1);
  csr_src[pos] = s;
}

// ---------------------------------------------------------------------------
// GAT aggregation (single pass, global-bound softmax shift — exact by
// shift-invariance). Memory-stream-bound at 64.5 us; unchanged except gmax
// now plain floats.
// ---------------------------------------------------------------------------
__global__ void __launch_bounds__(256) gat_aggregate(
    const __hip_bfloat16* __restrict__ hb, const float* __restrict__ a_src,
    const float* __restrict__ a_dst, const int* __restrict__ row_start,
    const int* __restrict__ csr_src, const float* __restrict__ bias,
    const float* __restrict__ gmaxf, int goff,
    __hip_bfloat16* __restrict__ out, int n) {
  __shared__ float plds[4][256];
  int wid = threadIdx.x >> 6;
  int lane = threadIdx.x & 63;
  int qh = lane >> 4;
  int node = (blockIdx.x << 2) + wid;
  if (node >= n) return;
  float4 adv = *(const float4*)(a_dst + (size_t)node * 4);
  float m0 = gmaxf[goff + 0] + adv.x; m0 = fmaxf(m0, NEG_SLOPE * m0);
  float m1 = gmaxf[goff + 1] + adv.y; m1 = fmaxf(m1, NEG_SLOPE * m1);
  float m2 = gmaxf[goff + 2] + adv.z; m2 = fmaxf(m2, NEG_SLOPE * m2);
  float m3 = gmaxf[goff + 3] + adv.w; m3 = fmaxf(m3, NEG_SLOPE * m3);
  int beg = __builtin_amdgcn_readfirstlane(row_start[node]);
  int end = __builtin_amdgcn_readfirstlane(row_start[node + 1]);
  const unsigned* hw = (const unsigned*)hb;

  float lq = 0.f, cq0 = 0.f, cq1 = 0.f, cq2 = 0.f, cq3 = 0.f;

  for (int cbeg = beg; cbeg < end; cbeg += 64) {
    int cnt = end - cbeg; if (cnt > 64) cnt = 64;
    int eidx = cbeg + (lane < cnt ? lane : cnt - 1);
    int s_l = csr_src[eidx];
    float4 as = *(const float4*)(a_src + (size_t)s_l * 4);
    float v0 = as.x + adv.x; v0 = fmaxf(v0, NEG_SLOPE * v0);
    float v1 = as.y + adv.y; v1 = fmaxf(v1, NEG_SLOPE * v1);
    float v2 = as.z + adv.z; v2 = fmaxf(v2, NEG_SLOPE * v2);
    float v3 = as.w + adv.w; v3 = fmaxf(v3, NEG_SLOPE * v3);
    float p0 = __expf(v0 - m0), p1 = __expf(v1 - m1);
    float p2 = __expf(v2 - m2), p3 = __expf(v3 - m3);
    *(float4*)&plds[wid][lane * 4] = make_float4(p0, p1, p2, p3);
    __builtin_amdgcn_s_waitcnt(0);

    auto step = [&](int jj) {
      int sj = __builtin_amdgcn_readlane(s_l, jj);
      float pq = plds[wid][jj * 4 + qh];
      uint2 d = *(const uint2*)(hw + (size_t)sj * 128 + 2 * lane);
      cq0 += pq * bflo(d.x); cq1 += pq * bfhi(d.x);
      cq2 += pq * bflo(d.y); cq3 += pq * bfhi(d.y);
      lq += pq;
    };
    int j = 0;
    for (; j + 4 <= cnt; j += 4) { step(j); step(j + 1); step(j + 2); step(j + 3); }
    for (; j < cnt; ++j) step(j);
  }

  float4 bq = *(const float4*)(bias + 4 * lane);
  float rq = 1.f / (lq + EPS);
  float o0 = fmaxf(cq0 * rq + bq.x, 0.f);
  float o1 = fmaxf(cq1 * rq + bq.y, 0.f);
  float o2 = fmaxf(cq2 * rq + bq.z, 0.f);
  float o3 = fmaxf(cq3 * rq + bq.w, 0.f);
  uint2 pk;
  pk.x = packbf2(o0, o1);
  pk.y = packbf2(o2, o3);
  *(uint2*)((unsigned*)out + (size_t)node * 128 + 2 * lane) = pk;
}

// ---------------------------------------------------------------------------
extern "C" void kernel_launch(void* const* d_in, const int* in_sizes, int n_in,
                              void* d_out, int out_size, void* d_ws, size_t ws_size,
                              hipStream_t stream) {
  const float* x      = (const float*)d_in[0];
  const int*   ei     = (const int*)d_in[1];
  const float* W1     = (const float*)d_in[2];
  const float* att_s1 = (const float*)d_in[3];
  const float* att_d1 = (const float*)d_in[4];
  const float* b1     = (const float*)d_in[5];
  const float* W2     = (const float*)d_in[6];
  const float* att_s2 = (const float*)d_in[7];
  const float* att_d2 = (const float*)d_in[8];
  const float* b2     = (const float*)d_in[9];
  const float* Wm1    = (const float*)d_in[10];
  const float* bm1    = (const float*)d_in[11];
  const float* Wm2    = (const float*)d_in[12];
  const float* bm2    = (const float*)d_in[13];
  float* out = (float*)d_out;

  int n = in_sizes[0] / 128;   // 50000
  int E = in_sizes[1] / 2;     // 800000
  int Etot = E + n;

  char* ws = (char*)d_ws;
  size_t off = 0;
  auto carve = [&](size_t bytes) {
    char* p = ws + off;
    off += (bytes + 255) & ~(size_t)255;
    return p;
  };
  __hip_bfloat16* hb   = (__hip_bfloat16*)carve((size_t)n * HC * 2);
  __hip_bfloat16* aggb = (__hip_bfloat16*)carve((size_t)n * HC * 2);
  __hip_bfloat16* xb   = (__hip_bfloat16*)carve((size_t)n * 128 * 2);
  __hip_bfloat16* W1t  = (__hip_bfloat16*)carve((size_t)128 * HC * 2);
  __hip_bfloat16* W2t  = (__hip_bfloat16*)carve((size_t)HC * HC * 2);
  __hip_bfloat16* Wm1t = (__hip_bfloat16*)carve((size_t)HC * HID * 2);
  __hip_bfloat16* Wm2t = (__hip_bfloat16*)carve((size_t)HID * 121 * 2);
  float* as   = (float*)carve((size_t)n * HEADS * 4);
  float* ad   = (float*)carve((size_t)n * HEADS * 4);
  int*   deg  = (int*)carve((size_t)n * 4);
  int*   row  = (int*)carve((size_t)(n + 1) * 4);
  int*   cur  = (int*)carve((size_t)n * 4);
  int*   csr  = (int*)carve((size_t)Etot * 4);
  int*   bsum = (int*)carve((size_t)1024 * 4);
  float* blockmax = (float*)carve((size_t)((n + 63) / 64) * 4 * 4);
  float* gmaxf    = (float*)carve((size_t)8 * 4);
  (void)ws_size;

  int nb256 = (n + 255) / 256;
  int rows64 = (n + 63) / 64;

  // --- input casts / weight prep ---
  cast_bf16<<<(n * 32 + 255) / 256, 256, 0, stream>>>(x, xb, n * 32);
  prep_weights<<<(122432 + 255) / 256, 256, 0, stream>>>(W1, W2, Wm1, Wm2, W1t, W2t, Wm1t, Wm2t);

  // --- CSR build ---
  deg_init<<<nb256, 256, 0, stream>>>(deg, n);
  deg_count<<<(E + 255) / 256, 256, 0, stream>>>(ei, E, deg);
  scan_block<<<nb256, 256, 0, stream>>>(deg, row, bsum, n);
  scan_partials<<<1, 256, 0, stream>>>(bsum, nb256);
  finalize_row<<<nb256, 256, 0, stream>>>(row, bsum, deg, cur, n);
  csr_fill<<<(Etot + 255) / 256, 256, 0, stream>>>(ei, E, n, cur, csr);

  // --- conv1 ---
  conv_gemm_attn<<<rows64, 256, 0, stream>>>(
      xb, W1t, hb, att_s1, att_d1, as, ad, blockmax, n, 128);
  reduce_gmax<<<1, 256, 0, stream>>>(blockmax, gmaxf, 0, rows64);
  gat_aggregate<<<(n + 3) / 4, 256, 0, stream>>>(hb, as, ad, row, csr, b1, gmaxf, 0, aggb, n);

  // --- conv2 ---
  conv_gemm_attn<<<rows64, 256, 0, stream>>>(
      aggb, W2t, hb, att_s2, att_d2, as, ad, blockmax, n, 256);
  reduce_gmax<<<1, 256, 0, stream>>>(blockmax, gmaxf, 4, rows64);
  gat_aggregate<<<(n + 3) / 4, 256, 0, stream>>>(hb, as, ad, row, csr, b2, gmaxf, 4, aggb, n);

  // --- post_mp ---
  postmp_fused<<<(n + 127) / 128, 256, 0, stream>>>(aggb, Wm1t, Wm2t, bm1, bm2, out, n);
}

// Round 8
// 404.582 us; speedup vs baseline: 1.2921x; 1.0077x over previous
//
#include <hip/hip_runtime.h>
#include <hip/hip_bf16.h>
#include <float.h>

#define HEADS 4
#define HID 64
#define HC 256   // HEADS*HID
#define NEG_SLOPE 0.2f
#define EPS 1e-16f

typedef short bf16x8 __attribute__((ext_vector_type(8)));
typedef float f32x4 __attribute__((ext_vector_type(4)));
typedef unsigned short ushort8 __attribute__((ext_vector_type(8)));

__device__ __forceinline__ float bflo(unsigned u) { return __uint_as_float(u << 16); }
__device__ __forceinline__ float bfhi(unsigned u) { return __uint_as_float(u & 0xffff0000u); }
__device__ __forceinline__ unsigned packbf2(float a, float b) {
  __hip_bfloat16 ha = __float2bfloat16(a), hb = __float2bfloat16(b);
  unsigned short ua = *reinterpret_cast<unsigned short*>(&ha);
  unsigned short ub = *reinterpret_cast<unsigned short*>(&hb);
  return (unsigned)ua | ((unsigned)ub << 16);
}

#define PK 40  // padded LDS row stride (bf16 elems) — proven conflict-light

// ---------------------------------------------------------------------------
// Conv GEMM (R6, proven): 64 rows x 256 cols per block, double-buffered LDS
// with VGPR prefetch, fused attn-coef epilogue, blockmax store (no atomics).
// ---------------------------------------------------------------------------
__global__ void __launch_bounds__(256) conv_gemm_attn(
    const __hip_bfloat16* __restrict__ A, const __hip_bfloat16* __restrict__ Bt,
    __hip_bfloat16* __restrict__ Cb,
    const float* __restrict__ att_s, const float* __restrict__ att_d,
    float* __restrict__ a_s, float* __restrict__ a_d,
    float* __restrict__ blockmax, int M, int K) {
  __shared__ unsigned short As[2][64 * PK];
  __shared__ unsigned short Bs[2][256 * PK];
  int tid = threadIdx.x;
  int lane = tid & 63, w = tid >> 6;
  int col16 = lane & 15, quad = lane >> 4;
  int row0 = blockIdx.x * 64;
  const unsigned short* Ag = (const unsigned short*)A;
  const unsigned short* Bg = (const unsigned short*)Bt;

  int ar = tid >> 2;
  int ako = (tid & 3) << 3;
  int agr = row0 + ar; if (agr >= M) agr = M - 1;
  const unsigned short* aga = Ag + (size_t)agr * K + ako;

  f32x4 acc[4][4] = {};
  int niter = K >> 5;

  ushort8 pa, pb[4];
  pa = *(const ushort8*)(aga);
#pragma unroll
  for (int p = 0; p < 4; p++) {
    int i2 = tid + (p << 8);
    int br = i2 >> 2, bko = (i2 & 3) << 3;
    pb[p] = *(const ushort8*)(Bg + (size_t)br * K + bko);
  }
  *(ushort8*)(&As[0][ar * PK + ako]) = pa;
#pragma unroll
  for (int p = 0; p < 4; p++) {
    int i2 = tid + (p << 8);
    int br = i2 >> 2, bko = (i2 & 3) << 3;
    *(ushort8*)(&Bs[0][br * PK + bko]) = pb[p];
  }
  __syncthreads();

  for (int it = 0; it < niter; ++it) {
    int cur = it & 1, nxt = cur ^ 1;
    int k1 = (it + 1) << 5;
    if (it + 1 < niter) {
      pa = *(const ushort8*)(aga + k1);
#pragma unroll
      for (int p = 0; p < 4; p++) {
        int i2 = tid + (p << 8);
        int br = i2 >> 2, bko = (i2 & 3) << 3;
        pb[p] = *(const ushort8*)(Bg + (size_t)br * K + k1 + bko);
      }
    }
    bf16x8 a[4], b[4];
#pragma unroll
    for (int i = 0; i < 4; i++)
      a[i] = *(const bf16x8*)(&As[cur][(i * 16 + col16) * PK + quad * 8]);
#pragma unroll
    for (int j = 0; j < 4; j++)
      b[j] = *(const bf16x8*)(&Bs[cur][((w << 6) + j * 16 + col16) * PK + quad * 8]);
#pragma unroll
    for (int i = 0; i < 4; i++)
#pragma unroll
      for (int j = 0; j < 4; j++)
        acc[i][j] = __builtin_amdgcn_mfma_f32_16x16x32_bf16(a[i], b[j], acc[i][j], 0, 0, 0);
    if (it + 1 < niter) {
      *(ushort8*)(&As[nxt][ar * PK + ako]) = pa;
#pragma unroll
      for (int p = 0; p < 4; p++) {
        int i2 = tid + (p << 8);
        int br = i2 >> 2, bko = (i2 & 3) << 3;
        *(ushort8*)(&Bs[nxt][br * PK + bko]) = pb[p];
      }
    }
    __syncthreads();
  }

#pragma unroll
  for (int i = 0; i < 4; i++) {
#pragma unroll
    for (int j = 0; j < 4; j++) {
      int gc = (w << 6) + j * 16 + col16;
      int grb = row0 + i * 16 + quad * 4;
#pragma unroll
      for (int r = 0; r < 4; r++) {
        int gr = grb + r;
        if (gr < M) Cb[(size_t)gr * 256 + gc] = __float2bfloat16(acc[i][j][r]);
      }
    }
  }

  float ws4[4], wd4[4];
#pragma unroll
  for (int j = 0; j < 4; j++) {
    ws4[j] = att_s[(w << 6) + j * 16 + col16];
    wd4[j] = att_d[(w << 6) + j * 16 + col16];
  }
  float wavemax = -FLT_MAX;
#pragma unroll
  for (int i = 0; i < 4; i++) {
#pragma unroll
    for (int r = 0; r < 4; r++) {
      float vs = 0.f, vd = 0.f;
#pragma unroll
      for (int j = 0; j < 4; j++) {
        vs += acc[i][j][r] * ws4[j];
        vd += acc[i][j][r] * wd4[j];
      }
#pragma unroll
      for (int off = 1; off < 16; off <<= 1) {
        vs += __shfl_xor(vs, off);
        vd += __shfl_xor(vd, off);
      }
      int gr = row0 + i * 16 + quad * 4 + r;
      if (col16 == 0 && gr < M) {
        a_s[(size_t)gr * 4 + w] = vs;
        a_d[(size_t)gr * 4 + w] = vd;
      }
      wavemax = fmaxf(wavemax, vs);
    }
  }
  wavemax = fmaxf(wavemax, __shfl_xor(wavemax, 16));
  wavemax = fmaxf(wavemax, __shfl_xor(wavemax, 32));
  if (lane == 0) blockmax[(size_t)blockIdx.x * 4 + w] = wavemax;
}

// reduce blockmax[nb][4] -> gmaxf[goff+0..3]
__global__ void __launch_bounds__(256) reduce_gmax(const float* __restrict__ blockmax,
                                                   float* __restrict__ gmaxf, int goff, int nb) {
  __shared__ float wm[4][4];
  int tid = threadIdx.x, lane = tid & 63, w = tid >> 6;
  int hd = tid & 3;
  float m = -FLT_MAX;
  for (int i = tid >> 2; i < nb; i += 64)
    m = fmaxf(m, blockmax[(size_t)i * 4 + hd]);
#pragma unroll
  for (int off = 4; off < 64; off <<= 1)
    m = fmaxf(m, __shfl_xor(m, off));
  if (lane < 4) wm[w][lane] = m;
  __syncthreads();
  if (tid < 4) {
    float r = fmaxf(fmaxf(wm[0][tid], wm[1][tid]), fmaxf(wm[2][tid], wm[3][tid]));
    gmaxf[goff + tid] = r;
  }
}

// ---------------------------------------------------------------------------
// Fused post_mp with dbuf stage 1; T aliases the stage-1 LDS (barrier-safe).
// out = sigmoid((aggb@Wm1 + bm1) @ Wm2 + bm2)
// ---------------------------------------------------------------------------
#define TS 72

__global__ void __launch_bounds__(256) postmp_fused(
    const __hip_bfloat16* __restrict__ A, const __hip_bfloat16* __restrict__ Wm1t,
    const __hip_bfloat16* __restrict__ Wm2t, const float* __restrict__ bm1,
    const float* __restrict__ bm2, float* __restrict__ out, int M) {
  // region0: stage1 dbuf As[2][128*PK] (0..10239) + Bs[2][64*PK] (10240..15359)
  //          then T[128*TS] aliases 0..9215 after barrier
  // region1: W2s[128*TS] at 15360..24575
  __shared__ unsigned short smem[24576];
  unsigned short* W2s = &smem[15360];
  int tid = threadIdx.x;
  int lane = tid & 63, w = tid >> 6;
  int col16 = lane & 15, quad = lane >> 4;
  int row0 = blockIdx.x * 128;
  const unsigned short* Ag = (const unsigned short*)A;
  const unsigned short* Bg = (const unsigned short*)Wm1t;
  const unsigned short* W2g = (const unsigned short*)Wm2t;

  // stage Wm2t [121][64] -> W2s (zero-pad rows 121..127); not aliased, safe now
#pragma unroll
  for (int c = tid; c < 1024; c += 256) {
    int r = c >> 3, ko = (c & 7) << 3;
    ushort8 v = {};
    if (r < 121) v = *(const ushort8*)(W2g + (size_t)r * 64 + ko);
    *(ushort8*)(&W2s[r * TS + ko]) = v;
  }

  // ---- stage 1 with double buffer: t1 = A@Wm1 + bm1 ----
  // A granules: 512/tile, 2 per thread; B granules: 256/tile, 1 per thread
  int ar0 = tid >> 2, ako = (tid & 3) << 3;
  int agr0 = row0 + ar0;       if (agr0 >= M) agr0 = M - 1;
  int agr1 = row0 + ar0 + 64;  if (agr1 >= M) agr1 = M - 1;
  const unsigned short* aga0 = Ag + (size_t)agr0 * 256 + ako;
  const unsigned short* aga1 = Ag + (size_t)agr1 * 256 + ako;
  int br = tid >> 2, bko = (tid & 3) << 3;
  const unsigned short* bga = Bg + (size_t)br * 256 + bko;

  f32x4 acc1[2][4] = {};
  ushort8 pa0, pa1, pbv;
  pa0 = *(const ushort8*)(aga0);
  pa1 = *(const ushort8*)(aga1);
  pbv = *(const ushort8*)(bga);
  *(ushort8*)(&smem[ar0 * PK + ako]) = pa0;
  *(ushort8*)(&smem[(ar0 + 64) * PK + ako]) = pa1;
  *(ushort8*)(&smem[10240 + br * PK + bko]) = pbv;
  __syncthreads();

  for (int it = 0; it < 8; ++it) {
    int cur = it & 1, nxt = cur ^ 1;
    unsigned short* Asc = &smem[cur * 5120];
    unsigned short* Bsc = &smem[10240 + cur * 2560];
    int k1 = (it + 1) << 5;
    if (it + 1 < 8) {
      pa0 = *(const ushort8*)(aga0 + k1);
      pa1 = *(const ushort8*)(aga1 + k1);
      pbv = *(const ushort8*)(bga + k1);
    }
    bf16x8 a[2], b[4];
#pragma unroll
    for (int i = 0; i < 2; i++)
      a[i] = *(const bf16x8*)(&Asc[(w * 32 + i * 16 + col16) * PK + quad * 8]);
#pragma unroll
    for (int j = 0; j < 4; j++)
      b[j] = *(const bf16x8*)(&Bsc[(j * 16 + col16) * PK + quad * 8]);
#pragma unroll
    for (int i = 0; i < 2; i++)
#pragma unroll
      for (int j = 0; j < 4; j++)
        acc1[i][j] = __builtin_amdgcn_mfma_f32_16x16x32_bf16(a[i], b[j], acc1[i][j], 0, 0, 0);
    if (it + 1 < 8) {
      unsigned short* Asn = &smem[nxt * 5120];
      unsigned short* Bsn = &smem[10240 + nxt * 2560];
      *(ushort8*)(&Asn[ar0 * PK + ako]) = pa0;
      *(ushort8*)(&Asn[(ar0 + 64) * PK + ako]) = pa1;
      *(ushort8*)(&Bsn[br * PK + bko]) = pbv;
    }
    __syncthreads();
  }

  // t1 -> LDS (bf16, aliases stage-1 buffers; all stage-1 reads done)
  unsigned short* T = &smem[0];
#pragma unroll
  for (int i = 0; i < 2; i++) {
#pragma unroll
    for (int j = 0; j < 4; j++) {
      int col = j * 16 + col16;
      float bv = bm1[col];
#pragma unroll
      for (int r = 0; r < 4; r++) {
        int rl = w * 32 + i * 16 + quad * 4 + r;
        __hip_bfloat16 hv = __float2bfloat16(acc1[i][j][r] + bv);
        T[rl * TS + col] = *reinterpret_cast<unsigned short*>(&hv);
      }
    }
  }
  __syncthreads();

  // ---- stage 2 ----
  int wm2 = w & 1, wn2 = w >> 1;
  f32x4 acc2[4][4] = {};
#pragma unroll
  for (int kk = 0; kk < 2; kk++) {
    bf16x8 a[4], b[4];
#pragma unroll
    for (int i = 0; i < 4; i++)
      a[i] = *(const bf16x8*)(&T[(wm2 * 64 + i * 16 + col16) * TS + kk * 32 + quad * 8]);
#pragma unroll
    for (int j = 0; j < 4; j++)
      b[j] = *(const bf16x8*)(&W2s[(wn2 * 64 + j * 16 + col16) * TS + kk * 32 + quad * 8]);
#pragma unroll
    for (int i = 0; i < 4; i++)
#pragma unroll
      for (int j = 0; j < 4; j++)
        acc2[i][j] = __builtin_amdgcn_mfma_f32_16x16x32_bf16(a[i], b[j], acc2[i][j], 0, 0, 0);
  }
#pragma unroll
  for (int i = 0; i < 4; i++) {
#pragma unroll
    for (int j = 0; j < 4; j++) {
      int gc = wn2 * 64 + j * 16 + col16;
      if (gc >= 121) continue;
      float bv = bm2[gc];
      int grb = row0 + wm2 * 64 + i * 16 + quad * 4;
#pragma unroll
      for (int r = 0; r < 4; r++) {
        int gr = grb + r;
        if (gr >= M) continue;
        float v = acc2[i][j][r] + bv;
        out[(size_t)gr * 121 + gc] = 1.f / (1.f + __expf(-v));
      }
    }
  }
}

// ---------------------------------------------------------------------------
// casts / weight prep
// ---------------------------------------------------------------------------
__global__ void cast_bf16(const float* __restrict__ src, __hip_bfloat16* __restrict__ dst, int count4) {
  int i = blockIdx.x * 256 + threadIdx.x;
  if (i >= count4) return;
  float4 v = *(const float4*)(src + 4 * (size_t)i);
  uint2 pk;
  pk.x = packbf2(v.x, v.y);
  pk.y = packbf2(v.z, v.w);
  *(uint2*)((unsigned*)dst + 2 * (size_t)i) = pk;
}

__global__ void prep_weights(const float* __restrict__ W1, const float* __restrict__ W2,
                             const float* __restrict__ Wm1, const float* __restrict__ Wm2,
                             __hip_bfloat16* __restrict__ W1t, __hip_bfloat16* __restrict__ W2t,
                             __hip_bfloat16* __restrict__ Wm1t, __hip_bfloat16* __restrict__ Wm2t) {
  int i = blockIdx.x * 256 + threadIdx.x;
  if (i < 128 * 256) {
    int nn = i / 128, kk = i - nn * 128;
    W1t[i] = __float2bfloat16(W1[(size_t)kk * 256 + nn]);
    return;
  }
  i -= 128 * 256;
  if (i < 256 * 256) {
    int nn = i / 256, kk = i - nn * 256;
    W2t[i] = __float2bfloat16(W2[(size_t)kk * 256 + nn]);
    return;
  }
  i -= 256 * 256;
  if (i < 256 * 64) {
    int nn = i / 256, kk = i - nn * 256;
    Wm1t[i] = __float2bfloat16(Wm1[(size_t)kk * 64 + nn]);
    return;
  }
  i -= 256 * 64;
  if (i < 64 * 121) {
    int nn = i / 64, kk = i - nn * 64;
    Wm2t[i] = __float2bfloat16(Wm2[(size_t)kk * 121 + nn]);
  }
}

// ---------------------------------------------------------------------------
// CSR build
// ---------------------------------------------------------------------------
__global__ void deg_init(int* __restrict__ deg, int n) {
  int i = blockIdx.x * 256 + threadIdx.x;
  if (i < n) deg[i] = 1;
}

__global__ void deg_count(const int* __restrict__ ei, int E, int* __restrict__ deg) {
  int i = blockIdx.x * 256 + threadIdx.x;
  if (i < E) atomicAdd(&deg[ei[E + i]], 1);
}

__global__ void __launch_bounds__(256) scan_block(const int* __restrict__ deg,
                                                  int* __restrict__ row_start,
                                                  int* __restrict__ bsum, int n) {
  __shared__ int wt[4];
  int tid = threadIdx.x, lane = tid & 63, w = tid >> 6;
  int i = blockIdx.x * 256 + tid;
  int v = (i < n) ? deg[i] : 0;
  int s = v;
#pragma unroll
  for (int off = 1; off < 64; off <<= 1) {
    int t = __shfl_up(s, off);
    if (lane >= off) s += t;
  }
  if (lane == 63) wt[w] = s;
  __syncthreads();
  int add = 0;
  if (w > 0) add += wt[0];
  if (w > 1) add += wt[1];
  if (w > 2) add += wt[2];
  if (i < n) row_start[i + 1] = s + add;
  if (tid == 0) bsum[blockIdx.x] = wt[0] + wt[1] + wt[2] + wt[3];
}

__global__ void __launch_bounds__(256) scan_partials(int* __restrict__ bsum, int nb) {
  __shared__ int wt[4];
  int tid = threadIdx.x, lane = tid & 63, w = tid >> 6;
  int v = (tid < nb) ? bsum[tid] : 0;
  int s = v;
#pragma unroll
  for (int off = 1; off < 64; off <<= 1) {
    int t = __shfl_up(s, off);
    if (lane >= off) s += t;
  }
  if (lane == 63) wt[w] = s;
  __syncthreads();
  int add = 0;
  if (w > 0) add += wt[0];
  if (w > 1) add += wt[1];
  if (w > 2) add += wt[2];
  if (tid < nb) bsum[tid] = s + add - v;
}

__global__ void finalize_row(int* __restrict__ row_start, const int* __restrict__ bsum_ex,
                             const int* __restrict__ deg, int* __restrict__ cur, int n) {
  int i = blockIdx.x * 256 + threadIdx.x;
  if (i == 0) row_start[0] = 0;
  if (i < n) {
    int v = row_start[i + 1] + bsum_ex[blockIdx.x];
    row_start[i + 1] = v;
    cur[i] = v - deg[i];
  }
}

__global__ void csr_fill(const int* __restrict__ ei, int E, int n,
                         int* __restrict__ cur, int* __restrict__ csr_src) {
  int i = blockIdx.x * 256 + threadIdx.x;
  int Etot = E + n;
  if (i >= Etot) return;
  int s, d;
  if (i < E) { s = ei[i]; d = ei[E + i]; }
  else { s = d = i - E; }
  int pos = atomicAdd(&cur[d], 1);
  csr_src[pos] = s;
}

// ---------------------------------------------------------------------------
// GAT aggregation, 2 edges/step variant. One wave per dst node.
// Channel ownership: 32 lanes cover one 512B h row; lane (lane&31) owns the
// 8 channels [8*l32, 8*l32+8) = one dwordx4. Wave halves (lane>>5) process
// edges j and j+1 of each pair: edge index via __shfl, weight via LDS
// broadcast. Halves merged by shfl_xor(32) at the end (sum split even/odd —
// exact). Softmax shift = per-head global bound (shift-invariance: exact).
// ---------------------------------------------------------------------------
__global__ void __launch_bounds__(256) gat_aggregate(
    const __hip_bfloat16* __restrict__ hb, const float* __restrict__ a_src,
    const float* __restrict__ a_dst, const int* __restrict__ row_start,
    const int* __restrict__ csr_src, const float* __restrict__ bias,
    const float* __restrict__ gmaxf, int goff,
    __hip_bfloat16* __restrict__ out, int n) {
  __shared__ float plds[4][256];
  int wid = threadIdx.x >> 6;
  int lane = threadIdx.x & 63;
  int half = lane >> 5;
  int l32 = lane & 31;
  int qh = l32 >> 3;  // head of channels 8*l32..8*l32+7
  int node = (blockIdx.x << 2) + wid;
  if (node >= n) return;
  float4 adv = *(const float4*)(a_dst + (size_t)node * 4);
  float m0 = gmaxf[goff + 0] + adv.x; m0 = fmaxf(m0, NEG_SLOPE * m0);
  float m1 = gmaxf[goff + 1] + adv.y; m1 = fmaxf(m1, NEG_SLOPE * m1);
  float m2 = gmaxf[goff + 2] + adv.z; m2 = fmaxf(m2, NEG_SLOPE * m2);
  float m3 = gmaxf[goff + 3] + adv.w; m3 = fmaxf(m3, NEG_SLOPE * m3);
  int beg = __builtin_amdgcn_readfirstlane(row_start[node]);
  int end = __builtin_amdgcn_readfirstlane(row_start[node + 1]);
  const uint4* hw4 = (const uint4*)hb;  // 32 uint4 per row

  float lq = 0.f;
  float c0 = 0.f, c1 = 0.f, c2 = 0.f, c3 = 0.f;
  float c4 = 0.f, c5 = 0.f, c6 = 0.f, c7 = 0.f;

  for (int cbeg = beg; cbeg < end; cbeg += 64) {
    int cnt = end - cbeg; if (cnt > 64) cnt = 64;
    int eidx = cbeg + (lane < cnt ? lane : cnt - 1);
    int s_l = csr_src[eidx];
    float4 as = *(const float4*)(a_src + (size_t)s_l * 4);
    float v0 = as.x + adv.x; v0 = fmaxf(v0, NEG_SLOPE * v0);
    float v1 = as.y + adv.y; v1 = fmaxf(v1, NEG_SLOPE * v1);
    float v2 = as.z + adv.z; v2 = fmaxf(v2, NEG_SLOPE * v2);
    float v3 = as.w + adv.w; v3 = fmaxf(v3, NEG_SLOPE * v3);
    float p0 = __expf(v0 - m0), p1 = __expf(v1 - m1);
    float p2 = __expf(v2 - m2), p3 = __expf(v3 - m3);
    *(float4*)&plds[wid][lane * 4] = make_float4(p0, p1, p2, p3);
    __builtin_amdgcn_s_waitcnt(0);  // ds_write visible to our ds_reads

    auto step = [&](int j) {  // processes edges j (lanes 0-31) and j+1 (lanes 32-63)
      int jj = j + half;
      bool dup = jj >= cnt;       // only possible on the last odd-count pair
      int jc = dup ? cnt - 1 : jj;
      int sj = __shfl(s_l, jc);
      float pq = plds[wid][jc * 4 + qh];
      if (dup) pq = 0.f;
      uint4 d = hw4[(size_t)sj * 32 + l32];
      c0 += pq * bflo(d.x); c1 += pq * bfhi(d.x);
      c2 += pq * bflo(d.y); c3 += pq * bfhi(d.y);
      c4 += pq * bflo(d.z); c5 += pq * bfhi(d.z);
      c6 += pq * bflo(d.w); c7 += pq * bfhi(d.w);
      lq += pq;
    };
    int j = 0;
    for (; j + 8 <= cnt; j += 8) { step(j); step(j + 2); step(j + 4); step(j + 6); }
    for (; j < cnt; j += 2) step(j);
  }

  // merge even/odd halves
  lq += __shfl_xor(lq, 32);
  c0 += __shfl_xor(c0, 32); c1 += __shfl_xor(c1, 32);
  c2 += __shfl_xor(c2, 32); c3 += __shfl_xor(c3, 32);
  c4 += __shfl_xor(c4, 32); c5 += __shfl_xor(c5, 32);
  c6 += __shfl_xor(c6, 32); c7 += __shfl_xor(c7, 32);

  if (half == 0) {
    float4 bA = *(const float4*)(bias + 8 * l32);
    float4 bB = *(const float4*)(bias + 8 * l32 + 4);
    float rq = 1.f / (lq + EPS);
    float o0 = fmaxf(c0 * rq + bA.x, 0.f);
    float o1 = fmaxf(c1 * rq + bA.y, 0.f);
    float o2 = fmaxf(c2 * rq + bA.z, 0.f);
    float o3 = fmaxf(c3 * rq + bA.w, 0.f);
    float o4 = fmaxf(c4 * rq + bB.x, 0.f);
    float o5 = fmaxf(c5 * rq + bB.y, 0.f);
    float o6 = fmaxf(c6 * rq + bB.z, 0.f);
    float o7 = fmaxf(c7 * rq + bB.w, 0.f);
    uint4 pk;
    pk.x = packbf2(o0, o1);
    pk.y = packbf2(o2, o3);
    pk.z = packbf2(o4, o5);
    pk.w = packbf2(o6, o7);
    *(uint4*)((unsigned*)out + (size_t)node * 128 + l32 * 4) = pk;
  }
}

// ---------------------------------------------------------------------------
extern "C" void kernel_launch(void* const* d_in, const int* in_sizes, int n_in,
                              void* d_out, int out_size, void* d_ws, size_t ws_size,
                              hipStream_t stream) {
  const float* x      = (const float*)d_in[0];
  const int*   ei     = (const int*)d_in[1];
  const float* W1     = (const float*)d_in[2];
  const float* att_s1 = (const float*)d_in[3];
  const float* att_d1 = (const float*)d_in[4];
  const float* b1     = (const float*)d_in[5];
  const float* W2     = (const float*)d_in[6];
  const float* att_s2 = (const float*)d_in[7];
  const float* att_d2 = (const float*)d_in[8];
  const float* b2     = (const float*)d_in[9];
  const float* Wm1    = (const float*)d_in[10];
  const float* bm1    = (const float*)d_in[11];
  const float* Wm2    = (const float*)d_in[12];
  const float* bm2    = (const float*)d_in[13];
  float* out = (float*)d_out;

  int n = in_sizes[0] / 128;   // 50000
  int E = in_sizes[1] / 2;     // 800000
  int Etot = E + n;

  char* ws = (char*)d_ws;
  size_t off = 0;
  auto carve = [&](size_t bytes) {
    char* p = ws + off;
    off += (bytes + 255) & ~(size_t)255;
    return p;
  };
  __hip_bfloat16* hb   = (__hip_bfloat16*)carve((size_t)n * HC * 2);
  __hip_bfloat16* aggb = (__hip_bfloat16*)carve((size_t)n * HC * 2);
  __hip_bfloat16* xb   = (__hip_bfloat16*)carve((size_t)n * 128 * 2);
  __hip_bfloat16* W1t  = (__hip_bfloat16*)carve((size_t)128 * HC * 2);
  __hip_bfloat16* W2t  = (__hip_bfloat16*)carve((size_t)HC * HC * 2);
  __hip_bfloat16* Wm1t = (__hip_bfloat16*)carve((size_t)HC * HID * 2);
  __hip_bfloat16* Wm2t = (__hip_bfloat16*)carve((size_t)HID * 121 * 2);
  float* as   = (float*)carve((size_t)n * HEADS * 4);
  float* ad   = (float*)carve((size_t)n * HEADS * 4);
  int*   deg  = (int*)carve((size_t)n * 4);
  int*   row  = (int*)carve((size_t)(n + 1) * 4);
  int*   cur  = (int*)carve((size_t)n * 4);
  int*   csr  = (int*)carve((size_t)Etot * 4);
  int*   bsum = (int*)carve((size_t)1024 * 4);
  float* blockmax = (float*)carve((size_t)((n + 63) / 64) * 4 * 4);
  float* gmaxf    = (float*)carve((size_t)8 * 4);
  (void)ws_size;

  int nb256 = (n + 255) / 256;
  int rows64 = (n + 63) / 64;

  // --- input casts / weight prep ---
  cast_bf16<<<(n * 32 + 255) / 256, 256, 0, stream>>>(x, xb, n * 32);
  prep_weights<<<(122432 + 255) / 256, 256, 0, stream>>>(W1, W2, Wm1, Wm2, W1t, W2t, Wm1t, Wm2t);

  // --- CSR build ---
  deg_init<<<nb256, 256, 0, stream>>>(deg, n);
  deg_count<<<(E + 255) / 256, 256, 0, stream>>>(ei, E, deg);
  scan_block<<<nb256, 256, 0, stream>>>(deg, row, bsum, n);
  scan_partials<<<1, 256, 0, stream>>>(bsum, nb256);
  finalize_row<<<nb256, 256, 0, stream>>>(row, bsum, deg, cur, n);
  csr_fill<<<(Etot + 255) / 256, 256, 0, stream>>>(ei, E, n, cur, csr);

  // --- conv1 ---
  conv_gemm_attn<<<rows64, 256, 0, stream>>>(
      xb, W1t, hb, att_s1, att_d1, as, ad, blockmax, n, 128);
  reduce_gmax<<<1, 256, 0, stream>>>(blockmax, gmaxf, 0, rows64);
  gat_aggregate<<<(n + 3) / 4, 256, 0, stream>>>(hb, as, ad, row, csr, b1, gmaxf, 0, aggb, n);

  // --- conv2 ---
  conv_gemm_attn<<<rows64, 256, 0, stream>>>(
      aggb, W2t, hb, att_s2, att_d2, as, ad, blockmax, n, 256);
  reduce_gmax<<<1, 256, 0, stream>>>(blockmax, gmaxf, 4, rows64);
  gat_aggregate<<<(n + 3) / 4, 256, 0, stream>>>(hb, as, ad, row, csr, b2, gmaxf, 4, aggb, n);

  // --- post_mp ---
  postmp_fused<<<(n + 127) / 128, 256, 0, stream>>>(aggb, Wm1t, Wm2t, bm1, bm2, out, n);
}